// Round 8
// baseline (263.379 us; speedup 1.0000x reference)
//
#include <hip/hip_runtime.h>
#include <hip/hip_bf16.h>

#define B_  4
#define T_  2048
#define D_  768
#define H_  12
#define DH_ 64
#define FF_ 3072

typedef __attribute__((ext_vector_type(8))) short bf16x8;
typedef __attribute__((ext_vector_type(4))) float f32x4;
typedef __attribute__((ext_vector_type(4))) unsigned short us4;

#define MFMA16(a, b, c) __builtin_amdgcn_mfma_f32_16x16x32_bf16((a), (b), (c), 0, 0, 0)

__device__ __forceinline__ unsigned short f2bf(float f) {
    union { float f; unsigned u; } v; v.f = f;
    unsigned r = v.u + 0x7fffu + ((v.u >> 16) & 1u);
    return (unsigned short)(r >> 16);
}
__device__ __forceinline__ float bf2f(unsigned short s) {
    union { unsigned u; float f; } v; v.u = ((unsigned)s) << 16;
    return v.f;
}

// async global->LDS, 16B per lane. LDS dest must be wave-uniform; HW adds lane*16.
__device__ __forceinline__ void gload_lds16(const unsigned short* gp, unsigned short* lp) {
    __builtin_amdgcn_global_load_lds(
        (const __attribute__((address_space(1))) unsigned int*)gp,
        (__attribute__((address_space(3))) unsigned int*)lp,
        16, 0, 0);
}

// ---------------- weight convert + transpose: src[K][N] f32 -> dst[N][K] bf16 ----------
__global__ __launch_bounds__(256) void tcvt_kernel(
    const float* __restrict__ src, unsigned short* __restrict__ dst, int K, int N)
{
    __shared__ float tile[32][33];
    const int bx = blockIdx.x * 32;  // N dim
    const int by = blockIdx.y * 32;  // K dim
    const int tx = threadIdx.x, ty = threadIdx.y;  // 32 x 8
#pragma unroll
    for (int i = 0; i < 32; i += 8)
        tile[ty + i][tx] = src[(size_t)(by + ty + i) * N + bx + tx];
    __syncthreads();
#pragma unroll
    for (int i = 0; i < 32; i += 8)
        dst[(size_t)(bx + ty + i) * K + by + tx] = f2bf(tile[tx][ty + i]);
}

// batched version for the four 768x768 weights (Wq,Wk,Wv,Wo -> contiguous dst)
__global__ __launch_bounds__(256) void tcvt4_kernel(
    const float* __restrict__ s0, const float* __restrict__ s1,
    const float* __restrict__ s2, const float* __restrict__ s3,
    unsigned short* __restrict__ dst)
{
    __shared__ float tile[32][33];
    const int z = blockIdx.z;
    const float* src = (z == 0) ? s0 : (z == 1) ? s1 : (z == 2) ? s2 : s3;
    unsigned short* d = dst + (size_t)z * 589824;
    const int bx = blockIdx.x * 32;
    const int by = blockIdx.y * 32;
    const int tx = threadIdx.x, ty = threadIdx.y;
#pragma unroll
    for (int i = 0; i < 32; i += 8)
        tile[ty + i][tx] = src[(size_t)(by + ty + i) * 768 + bx + tx];
    __syncthreads();
#pragma unroll
    for (int i = 0; i < 32; i += 8)
        d[(size_t)(bx + ty + i) * 768 + by + tx] = f2bf(tile[tx][ty + i]);
}

// ---------------- LayerNorm: fp32 in -> bf16 out ----------------
__global__ __launch_bounds__(256) void ln_kernel(
    const float* __restrict__ x, const float* __restrict__ g,
    const float* __restrict__ be, unsigned short* __restrict__ out)
{
    const int row = blockIdx.x;
    const int t = threadIdx.x;
    const float* xr = x + (size_t)row * D_;
    float v0 = xr[t], v1 = xr[t + 256], v2 = xr[t + 512];
    float s = v0 + v1 + v2;
    float s2 = v0 * v0 + v1 * v1 + v2 * v2;
#pragma unroll
    for (int o = 1; o < 64; o <<= 1) {
        s  += __shfl_xor(s,  o);
        s2 += __shfl_xor(s2, o);
    }
    __shared__ float rs[4], rq[4];
    const int wave = t >> 6;
    if ((t & 63) == 0) { rs[wave] = s; rq[wave] = s2; }
    __syncthreads();
    s  = rs[0] + rs[1] + rs[2] + rs[3];
    s2 = rq[0] + rq[1] + rq[2] + rq[3];
    const float mu = s * (1.0f / D_);
    const float var = s2 * (1.0f / D_) - mu * mu;
    const float rstd = rsqrtf(var + 1e-5f);
    unsigned short* orow = out + (size_t)row * D_;
    orow[t]       = f2bf((v0 - mu) * rstd * g[t]       + be[t]);
    orow[t + 256] = f2bf((v1 - mu) * rstd * g[t + 256] + be[t + 256]);
    orow[t + 512] = f2bf((v2 - mu) * rstd * g[t + 512] + be[t + 512]);
}

// ---- fused split-K reduce + residual + LayerNorm (Wo path) ----
__global__ __launch_bounds__(256) void reduce_ln_kernel(
    const unsigned short* __restrict__ p0, const unsigned short* __restrict__ p1,
    const float* __restrict__ x, const float* __restrict__ bo,
    const float* __restrict__ g, const float* __restrict__ be,
    float* __restrict__ x2, unsigned short* __restrict__ h2)
{
    const int row = blockIdx.x;
    const int t = threadIdx.x;
    const size_t base = (size_t)row * D_;
    float v[3];
    float s = 0.0f, s2 = 0.0f;
#pragma unroll
    for (int j = 0; j < 3; ++j) {
        const int c = t + j * 256;
        const float vv = bf2f(p0[base + c]) + bf2f(p1[base + c]) + bo[c] + x[base + c];
        v[j] = vv;
        x2[base + c] = vv;
        s += vv; s2 += vv * vv;
    }
#pragma unroll
    for (int o = 1; o < 64; o <<= 1) {
        s  += __shfl_xor(s,  o);
        s2 += __shfl_xor(s2, o);
    }
    __shared__ float rs[4], rq[4];
    const int wave = t >> 6;
    if ((t & 63) == 0) { rs[wave] = s; rq[wave] = s2; }
    __syncthreads();
    s  = rs[0] + rs[1] + rs[2] + rs[3];
    s2 = rq[0] + rq[1] + rq[2] + rq[3];
    const float mu = s * (1.0f / D_);
    const float var = s2 * (1.0f / D_) - mu * mu;
    const float rstd = rsqrtf(var + 1e-5f);
#pragma unroll
    for (int j = 0; j < 3; ++j) {
        const int c = t + j * 256;
        h2[base + c] = f2bf((v[j] - mu) * rstd * g[c] + be[c]);
    }
}

// ---- split-K reduce + bias + residual (FF2 path, fp32 out) ----
__global__ __launch_bounds__(256) void reduce_out_kernel(
    const unsigned short* __restrict__ p0, const unsigned short* __restrict__ p1,
    const float* __restrict__ x2, const float* __restrict__ b2,
    float* __restrict__ out)
{
    const int n4 = B_ * T_ * D_ / 4;
    for (int i = blockIdx.x * 256 + threadIdx.x; i < n4; i += gridDim.x * 256) {
        const us4 a = ((const us4*)p0)[i];
        const us4 b = ((const us4*)p1)[i];
        const float4 xr = ((const float4*)x2)[i];
        const int col = (i * 4) % D_;
        float4 o;
        o.x = bf2f(a[0]) + bf2f(b[0]) + b2[col]     + xr.x;
        o.y = bf2f(a[1]) + bf2f(b[1]) + b2[col + 1] + xr.y;
        o.z = bf2f(a[2]) + bf2f(b[2]) + b2[col + 2] + xr.z;
        o.w = bf2f(a[3]) + bf2f(b[3]) + b2[col + 3] + xr.w;
        ((float4*)out)[i] = o;
    }
}

// ---------------- 128^2 GEMM (proven round-3 structure) ----------------
// BM=128, BN=128, BK=64; 512 threads (8 waves 4x2), wave-tile 32x64 (acc 2x4);
// LDS 32KB; co-residency hides latency. XOR-swizzled LDS (0 conflicts measured).
// Split-K via grid dim: ks = swz / nTilesMN.
// MODE 0: bf16 out; MODE 2: gelu->bf16; MODE 4: fused QKV; MODE 5: bf16 partial.
template<int MODE>
__global__ __launch_bounds__(512) void gemm512(
    const unsigned short* __restrict__ A,
    const unsigned short* __restrict__ Bt,
    const float* __restrict__ bias,
    const float* __restrict__ bias2,
    const float* __restrict__ bias3,
    void* __restrict__ outp,
    void* __restrict__ out2,
    void* __restrict__ out3,
    int N, int K, int kLen, int nTilesN, int nTilesMN, long partStride)
{
    __shared__ __align__(16) unsigned short As[128 * 64];
    __shared__ __align__(16) unsigned short Bs[128 * 64];

    const int nwg = gridDim.x;
    const int q = nwg >> 3, rr = nwg & 7;
    const int xcd = blockIdx.x & 7, loc = blockIdx.x >> 3;
    const int swz = (xcd < rr ? xcd * (q + 1) : rr * (q + 1) + (xcd - rr) * q) + loc;
    const int ks  = swz / nTilesMN;
    const int rem = swz - ks * nTilesMN;
    const int m0 = (rem / nTilesN) * 128;
    const int n0 = (rem % nTilesN) * 128;
    const int kOff = ks * kLen;

    const int tid = threadIdx.x;
    const int wv = tid >> 6;
    const int lane = tid & 63;
    const int wr = wv >> 1;
    const int wc = wv & 1;

    f32x4 zero4 = {0.0f, 0.0f, 0.0f, 0.0f};
    f32x4 acc[2][4];
#pragma unroll
    for (int i = 0; i < 2; ++i)
#pragma unroll
        for (int j = 0; j < 4; ++j) acc[i][j] = zero4;

    const int lrow = lane >> 3;
    const int scb = (lane & 7) ^ lrow;
    const size_t ag0 = (size_t)(m0 + wv * 16 + lrow) * K + kOff + scb * 8;
    const size_t ag1 = ag0 + (size_t)8 * K;
    const size_t bg0 = (size_t)(n0 + wv * 16 + lrow) * K + kOff + scb * 8;
    const size_t bg1 = bg0 + (size_t)8 * K;
    unsigned short* AsW = As + wv * 1024;
    unsigned short* BsW = Bs + wv * 1024;

    const int fr = lane & 15;
    const int fg = lane >> 4;
    const int sw = fr & 7;

    const int nk = kLen >> 6;
    for (int kt = 0; kt < nk; ++kt) {
        const int k0 = kt << 6;
        __syncthreads();
        gload_lds16(A  + ag0 + k0, AsW);
        gload_lds16(A  + ag1 + k0, AsW + 512);
        gload_lds16(Bt + bg0 + k0, BsW);
        gload_lds16(Bt + bg1 + k0, BsW + 512);
        __syncthreads();
#pragma unroll
        for (int kk = 0; kk < 2; ++kk) {
            bf16x8 afr[2], bfr[4];
#pragma unroll
            for (int mm = 0; mm < 2; ++mm) {
                const int row = wr * 32 + mm * 16 + fr;
                afr[mm] = *(const bf16x8*)(As + row * 64 + (((kk * 4 + fg) ^ sw) << 3));
            }
#pragma unroll
            for (int nn = 0; nn < 4; ++nn) {
                const int row = wc * 64 + nn * 16 + fr;
                bfr[nn] = *(const bf16x8*)(Bs + row * 64 + (((kk * 4 + fg) ^ sw) << 3));
            }
#pragma unroll
            for (int mm = 0; mm < 2; ++mm)
#pragma unroll
                for (int nn = 0; nn < 4; ++nn)
                    acc[mm][nn] = MFMA16(afr[mm], bfr[nn], acc[mm][nn]);
        }
    }

    const int lc = lane & 15;
    const int lr = (lane >> 4) * 4;
#pragma unroll
    for (int mm = 0; mm < 2; ++mm) {
        const int gm0 = m0 + wr * 32 + mm * 16 + lr;
#pragma unroll
        for (int nn = 0; nn < 4; ++nn) {
            const int gn = n0 + wc * 64 + nn * 16 + lc;
            if (MODE == 4) {
                if (gn < 1536) {
                    const float bv = (gn < 768) ? bias[gn] : bias2[gn - 768];
                    unsigned short* o = (gn < 768) ? (unsigned short*)outp : (unsigned short*)out2;
                    const int col = (gn < 768) ? gn : gn - 768;
#pragma unroll
                    for (int r = 0; r < 4; ++r)
                        o[(size_t)(gm0 + r) * 768 + col] = f2bf(acc[mm][nn][r] + bv);
                } else {
                    const float bv = bias3[gn - 1536];
                    const int b = gm0 / T_;
                    const int tl = gm0 - b * T_;
                    us4 pk;
#pragma unroll
                    for (int r = 0; r < 4; ++r) pk[r] = f2bf(acc[mm][nn][r] + bv);
                    *(us4*)((unsigned short*)out3 + ((size_t)(b * D_ + gn - 1536)) * T_ + tl) = pk;
                }
            } else if (MODE == 5) {
                unsigned short* o = (unsigned short*)outp + (size_t)ks * partStride;
#pragma unroll
                for (int r = 0; r < 4; ++r)
                    o[(size_t)(gm0 + r) * N + gn] = f2bf(acc[mm][nn][r]);
            } else {
                const float bv = bias[gn];
#pragma unroll
                for (int r = 0; r < 4; ++r) {
                    const int gm = gm0 + r;
                    float v = acc[mm][nn][r] + bv;
                    if (MODE == 0) {
                        ((unsigned short*)outp)[(size_t)gm * N + gn] = f2bf(v);
                    } else if (MODE == 2) {
                        v = 0.5f * v * (1.0f + erff(v * 0.70710678118654752f));
                        ((unsigned short*)outp)[(size_t)gm * N + gn] = f2bf(v);
                    }
                }
            }
        }
    }
}

// ---------------- 256^2 deep-pipelined GEMM (m201-style) + GELU epilogue ----------
// BM=BN=256, BK=32; 512 threads = 8 waves (2M x 4N), wave-tile 128x64 (acc 8x4).
// Fragment economy: 32 MFMA per 12 ds_read_b128 (2.67) vs 1.33 at 128^2.
// TRI-buffered LDS (3 x 32KB = 96KB, 1 block/CU), prefetch depth 2.
// 4 sub-phases per K-tile: {ds_read subtile | 1 half-tile stage issue ->
//   lgkmcnt(0) -> setprio(1) + 8 MFMA -> barrier}. Counted vmcnt(4) once per
// K-tile (tile t+2's 4 loads stay in flight); never drains mid-loop.
// Row = 32 shorts = 4 x 16B blocks; block b of row r stored at b ^ ((r>>1)&3)
// via pre-swizzled global source (gload dest linear); ds_read same XOR.
// -> max 2 lanes/bank (free). RAW: vmcnt(4)+barrier at end of tile t-1
// guarantees tile t fully in LDS. WAR: reads of buf complete at per-phase
// lgkmcnt(0) before the barrier that precedes any stage into it.
__global__ __launch_bounds__(512, 2) void gemm256_gelu(
    const unsigned short* __restrict__ A,
    const unsigned short* __restrict__ Bt,
    const float* __restrict__ bias,
    unsigned short* __restrict__ outp,
    int N, int K, int nTilesN)
{
    extern __shared__ __align__(16) unsigned short lds[];   // 3 x 16384 shorts

    const int nwg = gridDim.x;
    const int q = nwg >> 3, rr = nwg & 7;
    const int xcd = blockIdx.x & 7, loc = blockIdx.x >> 3;
    const int swz = (xcd < rr ? xcd * (q + 1) : rr * (q + 1) + (xcd - rr) * q) + loc;
    const int m0 = (swz / nTilesN) * 256;
    const int n0 = (swz % nTilesN) * 256;

    const int tid = threadIdx.x;
    const int wv = tid >> 6;
    const int lane = tid & 63;
    const int wm = wv >> 2;          // 0..1
    const int wn = wv & 3;           // 0..3

    f32x4 zero4 = {0.0f, 0.0f, 0.0f, 0.0f};
    f32x4 acc[8][4];
#pragma unroll
    for (int i = 0; i < 8; ++i)
#pragma unroll
        for (int j = 0; j < 4; ++j) acc[i][j] = zero4;

    // staging: 4 wave-issues per K-tile: A-lo, A-hi, B-lo, B-hi (16 rows each).
    // lane -> (lrow=lane>>2, blk=lane&3); source block = blk ^ ((lrow>>1)&3)
    const int lrow = lane >> 2;
    const int scb  = (lane & 3) ^ ((lrow >> 1) & 3);
    const unsigned short* gA0 = A  + (size_t)(m0 + wv * 16 + lrow) * K + scb * 8;
    const unsigned short* gA1 = gA0 + (size_t)128 * K;
    const unsigned short* gB0 = Bt + (size_t)(n0 + wv * 16 + lrow) * K + scb * 8;
    const unsigned short* gB1 = gB0 + (size_t)128 * K;
    const int dA0 = wv * 512, dA1 = 4096 + wv * 512;
    const int dB0 = 8192 + wv * 512, dB1 = 12288 + wv * 512;

    // fragment reads: key(row)=(row>>1)&3 reduces to (fr>>1)&3 for all frags
    const int fr = lane & 15;
    const int fg = lane >> 4;
    const int rb = (fg ^ ((fr >> 1) & 3)) << 3;
    const int aOff = (wm * 128 + fr) * 32 + rb;        // + mm*512
    const int bOff = 8192 + (wn * 64 + fr) * 32 + rb;  // + nn*512

    unsigned short* pc = lds;            // tile t
    unsigned short* pn = lds + 16384;    // tile t+1
    unsigned short* ps = lds + 32768;    // stage target (tile t+2)

    const int nk = K >> 5;

    // prologue: stage tiles 0 and 1 (K advance = 32 shorts per tile)
    gload_lds16(gA0, pc + dA0); gload_lds16(gA1, pc + dA1);
    gload_lds16(gB0, pc + dB0); gload_lds16(gB1, pc + dB1);
    gload_lds16(gA0 + 32, pn + dA0); gload_lds16(gA1 + 32, pn + dA1);
    gload_lds16(gB0 + 32, pn + dB0); gload_lds16(gB1 + 32, pn + dB1);
    asm volatile("s_waitcnt vmcnt(4)" ::: "memory");   // tile 0 landed (per-wave)
    __builtin_amdgcn_s_barrier();
    asm volatile("" ::: "memory");

    for (int t = 0; t < nk; ++t) {
        const bool st = (t + 2 < nk);
        const int kc = (t + 2) << 5;

        // ---- phase 0: B frags + A rows 0-31 of wave slab
        bf16x8 b0v = *(const bf16x8*)(pc + bOff);
        bf16x8 b1v = *(const bf16x8*)(pc + bOff + 512);
        bf16x8 b2v = *(const bf16x8*)(pc + bOff + 1024);
        bf16x8 b3v = *(const bf16x8*)(pc + bOff + 1536);
        bf16x8 a0 = *(const bf16x8*)(pc + aOff);
        bf16x8 a1 = *(const bf16x8*)(pc + aOff + 512);
        if (st) gload_lds16(gA0 + kc, ps + dA0);
        asm volatile("s_waitcnt lgkmcnt(0)" ::: "memory");
        __builtin_amdgcn_sched_barrier(0);
        __builtin_amdgcn_s_setprio(1);
        acc[0][0] = MFMA16(a0, b0v, acc[0][0]);
        acc[0][1] = MFMA16(a0, b1v, acc[0][1]);
        acc[0][2] = MFMA16(a0, b2v, acc[0][2]);
        acc[0][3] = MFMA16(a0, b3v, acc[0][3]);
        acc[1][0] = MFMA16(a1, b0v, acc[1][0]);
        acc[1][1] = MFMA16(a1, b1v, acc[1][1]);
        acc[1][2] = MFMA16(a1, b2v, acc[1][2]);
        acc[1][3] = MFMA16(a1, b3v, acc[1][3]);
        __builtin_amdgcn_s_setprio(0);
        __builtin_amdgcn_s_barrier();
        asm volatile("" ::: "memory");

        // ---- phase 1: A rows 32-63
        a0 = *(const bf16x8*)(pc + aOff + 1024);
        a1 = *(const bf16x8*)(pc + aOff + 1536);
        if (st) gload_lds16(gA1 + kc, ps + dA1);
        asm volatile("s_waitcnt lgkmcnt(0)" ::: "memory");
        __builtin_amdgcn_sched_barrier(0);
        __builtin_amdgcn_s_setprio(1);
        acc[2][0] = MFMA16(a0, b0v, acc[2][0]);
        acc[2][1] = MFMA16(a0, b1v, acc[2][1]);
        acc[2][2] = MFMA16(a0, b2v, acc[2][2]);
        acc[2][3] = MFMA16(a0, b3v, acc[2][3]);
        acc[3][0] = MFMA16(a1, b0v, acc[3][0]);
        acc[3][1] = MFMA16(a1, b1v, acc[3][1]);
        acc[3][2] = MFMA16(a1, b2v, acc[3][2]);
        acc[3][3] = MFMA16(a1, b3v, acc[3][3]);
        __builtin_amdgcn_s_setprio(0);
        __builtin_amdgcn_s_barrier();
        asm volatile("" ::: "memory");

        // ---- phase 2: A rows 64-95
        a0 = *(const bf16x8*)(pc + aOff + 2048);
        a1 = *(const bf16x8*)(pc + aOff + 2560);
        if (st) gload_lds16(gB0 + kc, ps + dB0);
        asm volatile("s_waitcnt lgkmcnt(0)" ::: "memory");
        __builtin_amdgcn_sched_barrier(0);
        __builtin_amdgcn_s_setprio(1);
        acc[4][0] = MFMA16(a0, b0v, acc[4][0]);
        acc[4][1] = MFMA16(a0, b1v, acc[4][1]);
        acc[4][2] = MFMA16(a0, b2v, acc[4][2]);
        acc[4][3] = MFMA16(a0, b3v, acc[4][3]);
        acc[5][0] = MFMA16(a1, b0v, acc[5][0]);
        acc[5][1] = MFMA16(a1, b1v, acc[5][1]);
        acc[5][2] = MFMA16(a1, b2v, acc[5][2]);
        acc[5][3] = MFMA16(a1, b3v, acc[5][3]);
        __builtin_amdgcn_s_setprio(0);
        __builtin_amdgcn_s_barrier();
        asm volatile("" ::: "memory");

        // ---- phase 3: A rows 96-127 + counted vmcnt at tile boundary
        a0 = *(const bf16x8*)(pc + aOff + 3072);
        a1 = *(const bf16x8*)(pc + aOff + 3584);
        if (st) gload_lds16(gB1 + kc, ps + dB1);
        asm volatile("s_waitcnt lgkmcnt(0)" ::: "memory");
        __builtin_amdgcn_sched_barrier(0);
        __builtin_amdgcn_s_setprio(1);
        acc[6][0] = MFMA16(a0, b0v, acc[6][0]);
        acc[6][1] = MFMA16(a0, b1v, acc[6][1]);
        acc[6][2] = MFMA16(a0, b2v, acc[6][2]);
        acc[6][3] = MFMA16(a0, b3v, acc[6][3]);
        acc[7][0] = MFMA16(a1, b0v, acc[7][0]);
        acc[7][1] = MFMA16(a1, b1v, acc[7][1]);
        acc[7][2] = MFMA16(a1, b2v, acc[7][2]);
        acc[7][3] = MFMA16(a1, b3v, acc[7][3]);
        __builtin_amdgcn_s_setprio(0);
        if (st) asm volatile("s_waitcnt vmcnt(4)" ::: "memory");   // tile t+1 landed
        else    asm volatile("s_waitcnt vmcnt(0)" ::: "memory");
        __builtin_amdgcn_s_barrier();
        asm volatile("" ::: "memory");

        unsigned short* tmp = pc; pc = pn; pn = ps; ps = tmp;
    }

    // ---- epilogue: GELU(exact) -> bf16
    const int lc = lane & 15;
    const int lr = (lane >> 4) * 4;
#pragma unroll
    for (int mm = 0; mm < 8; ++mm) {
        const int gm0 = m0 + wm * 128 + mm * 16 + lr;
#pragma unroll
        for (int nn = 0; nn < 4; ++nn) {
            const int gn = n0 + wn * 64 + nn * 16 + lc;
            const float bv = bias[gn];
#pragma unroll
            for (int r = 0; r < 4; ++r) {
                float v = acc[mm][nn][r] + bv;
                v = 0.5f * v * (1.0f + erff(v * 0.70710678118654752f));
                outp[(size_t)(gm0 + r) * N + gn] = f2bf(v);
            }
        }
    }
}

// ---------------- banded flash attention ----------------
__global__ __launch_bounds__(256) void attn_kernel(
    const unsigned short* __restrict__ Q,    // [B*T][768]
    const unsigned short* __restrict__ Kg,   // [B*T][768]
    const unsigned short* __restrict__ Vt,   // [B][768][T]
    unsigned short* __restrict__ ctx)        // [B*T][768]
{
    __shared__ __align__(16) unsigned short Qs[64][72];
    __shared__ __align__(16) unsigned short KP[192 * 72];   // Ks, later Ps[64][200]
    __shared__ __align__(16) unsigned short Vts[64][200];

    const int tid = threadIdx.x;
    const int lane = tid & 63;
    const int w = tid >> 6;
    const int bid = blockIdx.x;
    const int qt = bid & 31;
    const int h = (bid >> 5) % H_;
    const int b = bid / (32 * H_);
    const int qs = qt * 64;
    const int t0 = qs >= 64 ? qs - 64 : 0;
    const int t1 = (qs + 128 < T_) ? qs + 128 : T_;
    const int KW = t1 - t0;

    for (int s = tid; s < 512; s += 256) {
        const int r = s >> 3, c8 = (s & 7) << 3;
        *(uint4*)&Qs[r][c8] =
            *(const uint4*)&Q[((size_t)(b * T_ + qs + r)) * D_ + h * DH_ + c8];
    }
    unsigned short* Ks = KP;
    for (int s = tid; s < 1536; s += 256) {
        const int r = s >> 3, c8 = (s & 7) << 3;
        uint4 val = {0, 0, 0, 0};
        if (r < KW)
            val = *(const uint4*)&Kg[((size_t)(b * T_ + t0 + r)) * D_ + h * DH_ + c8];
        *(uint4*)&Ks[r * 72 + c8] = val;
    }
    for (int s = tid; s < 1536; s += 256) {
        const int r = s / 24, c8 = (s % 24) << 3;
        uint4 val = {0, 0, 0, 0};
        if (c8 < KW)
            val = *(const uint4*)&Vt[((size_t)((b * H_ + h) * DH_ + r)) * T_ + t0 + c8];
        *(uint4*)&Vts[r][c8] = val;
    }
    __syncthreads();

    f32x4 zero4 = {0.0f, 0.0f, 0.0f, 0.0f};
    f32x4 sa[12];
#pragma unroll
    for (int i = 0; i < 12; ++i) sa[i] = zero4;
#pragma unroll
    for (int ks = 0; ks < 2; ++ks) {
        const bf16x8 aq = *(const bf16x8*)&Qs[w * 16 + (lane & 15)][ks * 32 + (lane >> 4) * 8];
#pragma unroll
        for (int cf = 0; cf < 12; ++cf) {
            const bf16x8 bk = *(const bf16x8*)&Ks[(cf * 16 + (lane & 15)) * 72 + ks * 32 + (lane >> 4) * 8];
            sa[cf] = MFMA16(aq, bk, sa[cf]);
        }
    }
    __syncthreads();

    const int lq = w * 16 + (lane >> 4) * 4;
    float mx[4] = {-1e30f, -1e30f, -1e30f, -1e30f};
#pragma unroll
    for (int cf = 0; cf < 12; ++cf) {
        const int key = t0 + cf * 16 + (lane & 15);
#pragma unroll
        for (int r = 0; r < 4; ++r) {
            const int dd = (qs + lq + r) - key;
            const bool ok = (key < t1) && (dd <= 64) && (dd >= -64);
            const float sv = ok ? sa[cf][r] * 0.125f : -1e30f;
            sa[cf][r] = sv;
            mx[r] = fmaxf(mx[r], sv);
        }
    }
#pragma unroll
    for (int r = 0; r < 4; ++r)
#pragma unroll
        for (int o = 1; o < 16; o <<= 1)
            mx[r] = fmaxf(mx[r], __shfl_xor(mx[r], o));

    unsigned short* Ps = KP;
    float sm[4] = {0.0f, 0.0f, 0.0f, 0.0f};
#pragma unroll
    for (int cf = 0; cf < 12; ++cf) {
#pragma unroll
        for (int r = 0; r < 4; ++r) {
            const float p = __expf(sa[cf][r] - mx[r]);
            sm[r] += p;
            Ps[(lq + r) * 200 + cf * 16 + (lane & 15)] = f2bf(p);
        }
    }
#pragma unroll
    for (int r = 0; r < 4; ++r)
#pragma unroll
        for (int o = 1; o < 16; o <<= 1)
            sm[r] += __shfl_xor(sm[r], o);

    f32x4 oa[4];
#pragma unroll
    for (int i = 0; i < 4; ++i) oa[i] = zero4;
#pragma unroll
    for (int ks = 0; ks < 6; ++ks) {
        const bf16x8 ap = *(const bf16x8*)&Ps[(w * 16 + (lane & 15)) * 200 + ks * 32 + (lane >> 4) * 8];
#pragma unroll
        for (int nf = 0; nf < 4; ++nf) {
            const bf16x8 bv = *(const bf16x8*)&Vts[nf * 16 + (lane & 15)][ks * 32 + (lane >> 4) * 8];
            oa[nf] = MFMA16(ap, bv, oa[nf]);
        }
    }
#pragma unroll
    for (int nf = 0; nf < 4; ++nf) {
#pragma unroll
        for (int r = 0; r < 4; ++r) {
            const float o = oa[nf][r] / sm[r];
            ctx[((size_t)(b * T_ + qs + lq + r)) * D_ + h * DH_ + nf * 16 + (lane & 15)] = f2bf(o);
        }
    }
}

// ---------------- orchestration ----------------
extern "C" void kernel_launch(void* const* d_in, const int* in_sizes, int n_in,
                              void* d_out, int out_size, void* d_ws, size_t ws_size,
                              hipStream_t stream)
{
    const float* x   = (const float*)d_in[0];
    const float* Wq  = (const float*)d_in[1];
    const float* bq  = (const float*)d_in[2];
    const float* Wk  = (const float*)d_in[3];
    const float* bk  = (const float*)d_in[4];
    const float* Wv  = (const float*)d_in[5];
    const float* bv  = (const float*)d_in[6];
    const float* Wo  = (const float*)d_in[7];
    const float* bo  = (const float*)d_in[8];
    const float* W1  = (const float*)d_in[9];
    const float* b1  = (const float*)d_in[10];
    const float* W2  = (const float*)d_in[11];
    const float* b2  = (const float*)d_in[12];
    const float* g1  = (const float*)d_in[13];
    const float* be1 = (const float*)d_in[14];
    const float* g2  = (const float*)d_in[15];
    const float* be2 = (const float*)d_in[16];
    float* out = (float*)d_out;

    unsigned short* wqkv_t = (unsigned short*)d_ws;        // 3 x [768][768]
    unsigned short* wo_t = wqkv_t + 3 * 589824;
    unsigned short* w1_t = wo_t + 589824;                  // [3072][768]
    unsigned short* w2_t = w1_t + 2359296;                 // [768][3072]
    unsigned short* hbuf = w2_t + 2359296;                 // h1, ctx, FF2-partials
    unsigned short* qbuf = hbuf + 6291456;                 // q, h2
    float* x2 = (float*)(qbuf + 6291456);                  // fp32 [8192][768]
    unsigned short* kbuf = (unsigned short*)(x2 + 6291456); // k, Wo-partials
    unsigned short* vtb  = kbuf + 6291456;                 // [4][768][2048]
    unsigned short* ffb  = kbuf;                           // [8192][3072]

    dim3 tb(32, 8);
    tcvt4_kernel<<<dim3(24, 24, 4), tb, 0, stream>>>(Wq, Wk, Wv, Wo, wqkv_t);
    tcvt_kernel<<<dim3(96, 24), tb, 0, stream>>>(W1, w1_t, 768, 3072);
    tcvt_kernel<<<dim3(24, 96), tb, 0, stream>>>(W2, w2_t, 3072, 768);

    ln_kernel<<<8192, 256, 0, stream>>>(x, g1, be1, hbuf);

    // fused QKV: N = 2304, routes Q->qbuf, K->kbuf, V->vtb(transposed)
    gemm512<4><<<64 * 18, 512, 0, stream>>>(
        hbuf, wqkv_t, bq, bk, bv, qbuf, kbuf, vtb, 2304, 768, 768, 18, 64 * 18, 0);

    attn_kernel<<<1536, 256, 0, stream>>>(qbuf, kbuf, vtb, hbuf);   // ctx -> hbuf

    // Wo: split-K S=2 (K'=384), bf16 partials into dead kbuf/vtb region
    gemm512<5><<<64 * 6 * 2, 512, 0, stream>>>(
        hbuf, wo_t, nullptr, nullptr, nullptr, kbuf, nullptr, nullptr,
        768, 768, 384, 6, 64 * 6, 6291456);

    // fused reduce + residual + LN2: x2 (fp32) and h2 (bf16 -> qbuf)
    reduce_ln_kernel<<<8192, 256, 0, stream>>>(
        kbuf, kbuf + 6291456, x, bo, g2, be2, x2, qbuf);

    // FF1: 256^2 deep-pipelined engine, gelu -> ffb (384 blocks, 96KB LDS)
    gemm256_gelu<<<32 * 12, 512, 3 * 32768, stream>>>(
        qbuf, w1_t, b1, ffb, 3072, 768, 12);

    // FF2: split-K S=2 (K'=1536), bf16 partials into dead hbuf/qbuf region
    gemm512<5><<<64 * 6 * 2, 512, 0, stream>>>(
        ffb, w2_t, nullptr, nullptr, nullptr, hbuf, nullptr, nullptr,
        768, 3072, 1536, 6, 64 * 6, 6291456);

    reduce_out_kernel<<<2048, 256, 0, stream>>>(
        hbuf, hbuf + 6291456, x2, b2, out);
}

// Round 9
// 238.938 us; speedup vs baseline: 1.1023x; 1.1023x over previous
//
#include <hip/hip_runtime.h>
#include <hip/hip_bf16.h>

#define B_  4
#define T_  2048
#define D_  768
#define H_  12
#define DH_ 64
#define FF_ 3072

typedef __attribute__((ext_vector_type(8))) short bf16x8;
typedef __attribute__((ext_vector_type(4))) float f32x4;
typedef __attribute__((ext_vector_type(4))) unsigned short us4;

#define MFMA16(a, b, c) __builtin_amdgcn_mfma_f32_16x16x32_bf16((a), (b), (c), 0, 0, 0)

__device__ __forceinline__ unsigned short f2bf(float f) {
    union { float f; unsigned u; } v; v.f = f;
    unsigned r = v.u + 0x7fffu + ((v.u >> 16) & 1u);
    return (unsigned short)(r >> 16);
}
__device__ __forceinline__ float bf2f(unsigned short s) {
    union { unsigned u; float f; } v; v.u = ((unsigned)s) << 16;
    return v.f;
}

// async global->LDS, 16B per lane. LDS dest must be wave-uniform; HW adds lane*16.
__device__ __forceinline__ void gload_lds16(const unsigned short* gp, unsigned short* lp) {
    __builtin_amdgcn_global_load_lds(
        (const __attribute__((address_space(1))) unsigned int*)gp,
        (__attribute__((address_space(3))) unsigned int*)lp,
        16, 0, 0);
}

// ---------------- weight convert + transpose: src[K][N] f32 -> dst[N][K] bf16 ----------
__global__ __launch_bounds__(256) void tcvt_kernel(
    const float* __restrict__ src, unsigned short* __restrict__ dst, int K, int N)
{
    __shared__ float tile[32][33];
    const int bx = blockIdx.x * 32;  // N dim
    const int by = blockIdx.y * 32;  // K dim
    const int tx = threadIdx.x, ty = threadIdx.y;  // 32 x 8
#pragma unroll
    for (int i = 0; i < 32; i += 8)
        tile[ty + i][tx] = src[(size_t)(by + ty + i) * N + bx + tx];
    __syncthreads();
#pragma unroll
    for (int i = 0; i < 32; i += 8)
        dst[(size_t)(bx + ty + i) * K + by + tx] = f2bf(tile[tx][ty + i]);
}

// batched version for the four 768x768 weights (Wq,Wk,Wv,Wo -> contiguous dst)
__global__ __launch_bounds__(256) void tcvt4_kernel(
    const float* __restrict__ s0, const float* __restrict__ s1,
    const float* __restrict__ s2, const float* __restrict__ s3,
    unsigned short* __restrict__ dst)
{
    __shared__ float tile[32][33];
    const int z = blockIdx.z;
    const float* src = (z == 0) ? s0 : (z == 1) ? s1 : (z == 2) ? s2 : s3;
    unsigned short* d = dst + (size_t)z * 589824;
    const int bx = blockIdx.x * 32;
    const int by = blockIdx.y * 32;
    const int tx = threadIdx.x, ty = threadIdx.y;
#pragma unroll
    for (int i = 0; i < 32; i += 8)
        tile[ty + i][tx] = src[(size_t)(by + ty + i) * 768 + bx + tx];
    __syncthreads();
#pragma unroll
    for (int i = 0; i < 32; i += 8)
        d[(size_t)(bx + ty + i) * 768 + by + tx] = f2bf(tile[tx][ty + i]);
}

// ---------------- LayerNorm: fp32 in -> bf16 out ----------------
__global__ __launch_bounds__(256) void ln_kernel(
    const float* __restrict__ x, const float* __restrict__ g,
    const float* __restrict__ be, unsigned short* __restrict__ out)
{
    const int row = blockIdx.x;
    const int t = threadIdx.x;
    const float* xr = x + (size_t)row * D_;
    float v0 = xr[t], v1 = xr[t + 256], v2 = xr[t + 512];
    float s = v0 + v1 + v2;
    float s2 = v0 * v0 + v1 * v1 + v2 * v2;
#pragma unroll
    for (int o = 1; o < 64; o <<= 1) {
        s  += __shfl_xor(s,  o);
        s2 += __shfl_xor(s2, o);
    }
    __shared__ float rs[4], rq[4];
    const int wave = t >> 6;
    if ((t & 63) == 0) { rs[wave] = s; rq[wave] = s2; }
    __syncthreads();
    s  = rs[0] + rs[1] + rs[2] + rs[3];
    s2 = rq[0] + rq[1] + rq[2] + rq[3];
    const float mu = s * (1.0f / D_);
    const float var = s2 * (1.0f / D_) - mu * mu;
    const float rstd = rsqrtf(var + 1e-5f);
    unsigned short* orow = out + (size_t)row * D_;
    orow[t]       = f2bf((v0 - mu) * rstd * g[t]       + be[t]);
    orow[t + 256] = f2bf((v1 - mu) * rstd * g[t + 256] + be[t + 256]);
    orow[t + 512] = f2bf((v2 - mu) * rstd * g[t + 512] + be[t + 512]);
}

// ---- fused split-K reduce + residual + LayerNorm (Wo path) ----
__global__ __launch_bounds__(256) void reduce_ln_kernel(
    const unsigned short* __restrict__ p0, const unsigned short* __restrict__ p1,
    const float* __restrict__ x, const float* __restrict__ bo,
    const float* __restrict__ g, const float* __restrict__ be,
    float* __restrict__ x2, unsigned short* __restrict__ h2)
{
    const int row = blockIdx.x;
    const int t = threadIdx.x;
    const size_t base = (size_t)row * D_;
    float v[3];
    float s = 0.0f, s2 = 0.0f;
#pragma unroll
    for (int j = 0; j < 3; ++j) {
        const int c = t + j * 256;
        const float vv = bf2f(p0[base + c]) + bf2f(p1[base + c]) + bo[c] + x[base + c];
        v[j] = vv;
        x2[base + c] = vv;
        s += vv; s2 += vv * vv;
    }
#pragma unroll
    for (int o = 1; o < 64; o <<= 1) {
        s  += __shfl_xor(s,  o);
        s2 += __shfl_xor(s2, o);
    }
    __shared__ float rs[4], rq[4];
    const int wave = t >> 6;
    if ((t & 63) == 0) { rs[wave] = s; rq[wave] = s2; }
    __syncthreads();
    s  = rs[0] + rs[1] + rs[2] + rs[3];
    s2 = rq[0] + rq[1] + rq[2] + rq[3];
    const float mu = s * (1.0f / D_);
    const float var = s2 * (1.0f / D_) - mu * mu;
    const float rstd = rsqrtf(var + 1e-5f);
#pragma unroll
    for (int j = 0; j < 3; ++j) {
        const int c = t + j * 256;
        h2[base + c] = f2bf((v[j] - mu) * rstd * g[c] + be[c]);
    }
}

// ---- split-K reduce + bias + residual (FF2 path, fp32 out) ----
__global__ __launch_bounds__(256) void reduce_out_kernel(
    const unsigned short* __restrict__ p0, const unsigned short* __restrict__ p1,
    const float* __restrict__ x2, const float* __restrict__ b2,
    float* __restrict__ out)
{
    const int n4 = B_ * T_ * D_ / 4;
    for (int i = blockIdx.x * 256 + threadIdx.x; i < n4; i += gridDim.x * 256) {
        const us4 a = ((const us4*)p0)[i];
        const us4 b = ((const us4*)p1)[i];
        const float4 xr = ((const float4*)x2)[i];
        const int col = (i * 4) % D_;
        float4 o;
        o.x = bf2f(a[0]) + bf2f(b[0]) + b2[col]     + xr.x;
        o.y = bf2f(a[1]) + bf2f(b[1]) + b2[col + 1] + xr.y;
        o.z = bf2f(a[2]) + bf2f(b[2]) + b2[col + 2] + xr.z;
        o.w = bf2f(a[3]) + bf2f(b[3]) + b2[col + 3] + xr.w;
        ((float4*)out)[i] = o;
    }
}

// ---------------- 4-wave m97-structure GEMM: C = A[M][K] * Bt[N][K]^T ----------------
// BM=BN=128, BK=64; 256 threads (4 waves 2x2), wave-tile 64x64 (acc 4x4).
// Fragment economy 0.5 ds_read/MFMA (vs 0.75 at 8-wave 32x64). LDS 32KB,
// ~3 blocks/CU co-residency hides latency (m114 mechanism). LDS rows = 64
// shorts = 8 x 16B blocks; block b of row r at b^(r&7) via pre-swizzled global
// SOURCE (gload dest linear); ds_read same XOR -> measured 0 bank conflicts.
// 1D grid over (ks, mTile, nTile), N-fastest; bijective XCD swizzle.
// Split-K: ks = swz / nTilesMN, K range [ks*kLen, (ks+1)*kLen).
// MODE 0: bf16 out; MODE 2: gelu->bf16; MODE 4: fused QKV routing;
// MODE 5: bf16 partial at outp + ks*partStride (no bias).
template<int MODE>
__global__ __launch_bounds__(256, 3) void gemm4w(
    const unsigned short* __restrict__ A,
    const unsigned short* __restrict__ Bt,
    const float* __restrict__ bias,
    const float* __restrict__ bias2,
    const float* __restrict__ bias3,
    void* __restrict__ outp,
    void* __restrict__ out2,
    void* __restrict__ out3,
    int N, int K, int kLen, int nTilesN, int nTilesMN, long partStride)
{
    __shared__ __align__(16) unsigned short As[128 * 64];
    __shared__ __align__(16) unsigned short Bs[128 * 64];

    // bijective XCD swizzle (m204)
    const int nwg = gridDim.x;
    const int q = nwg >> 3, rr = nwg & 7;
    const int xcd = blockIdx.x & 7, loc = blockIdx.x >> 3;
    const int swz = (xcd < rr ? xcd * (q + 1) : rr * (q + 1) + (xcd - rr) * q) + loc;
    const int ks  = swz / nTilesMN;
    const int rem = swz - ks * nTilesMN;
    const int m0 = (rem / nTilesN) * 128;
    const int n0 = (rem % nTilesN) * 128;
    const int kOff = ks * kLen;

    const int tid = threadIdx.x;
    const int wv = tid >> 6;
    const int lane = tid & 63;
    const int wr = wv >> 1;          // 0..1 (M)
    const int wc = wv & 1;           // 0..1 (N)

    f32x4 zero4 = {0.0f, 0.0f, 0.0f, 0.0f};
    f32x4 acc[4][4];
#pragma unroll
    for (int i = 0; i < 4; ++i)
#pragma unroll
        for (int j = 0; j < 4; ++j) acc[i][j] = zero4;

    // staging: each wave stages 32 rows of A and 32 rows of B (4 chunks of
    // 8 rows x 64 shorts each). lane -> (lrow=lane>>3, blk=lane&7);
    // source col-block = blk ^ lrow (chunk bases are multiples of 8 rows).
    const int lrow = lane >> 3;
    const int scb = (lane & 7) ^ lrow;
    const unsigned short* ag = A  + (size_t)(m0 + wv * 32 + lrow) * K + kOff + scb * 8;
    const unsigned short* bg = Bt + (size_t)(n0 + wv * 32 + lrow) * K + kOff + scb * 8;
    unsigned short* aLds = As + wv * 32 * 64;
    unsigned short* bLds = Bs + wv * 32 * 64;

    // fragment-read setup
    const int fr = lane & 15;
    const int fg = lane >> 4;        // 0..3
    const int sw = fr & 7;
    const int aRow = (wr * 64 + fr) * 64;   // + mm*16*64
    const int bRow = (wc * 64 + fr) * 64;   // + nn*16*64

    const int nk = kLen >> 6;
    for (int kt = 0; kt < nk; ++kt) {
        const int k0 = kt << 6;
        __syncthreads();
#pragma unroll
        for (int c = 0; c < 4; ++c)
            gload_lds16(ag + k0 + (size_t)c * 8 * K, aLds + c * 512);
#pragma unroll
        for (int c = 0; c < 4; ++c)
            gload_lds16(bg + k0 + (size_t)c * 8 * K, bLds + c * 512);
        __syncthreads();

#pragma unroll
        for (int kk = 0; kk < 2; ++kk) {
            bf16x8 afr[4], bfr[4];
            const int cb = ((kk * 4 + fg) ^ sw) << 3;
#pragma unroll
            for (int mm = 0; mm < 4; ++mm)
                afr[mm] = *(const bf16x8*)(As + aRow + mm * 1024 + cb);
#pragma unroll
            for (int nn = 0; nn < 4; ++nn)
                bfr[nn] = *(const bf16x8*)(Bs + bRow + nn * 1024 + cb);
#pragma unroll
            for (int mm = 0; mm < 4; ++mm)
#pragma unroll
                for (int nn = 0; nn < 4; ++nn)
                    acc[mm][nn] = MFMA16(afr[mm], bfr[nn], acc[mm][nn]);
        }
    }

    // ---- epilogue
    const int lc = lane & 15;
    const int lr = (lane >> 4) * 4;
#pragma unroll
    for (int mm = 0; mm < 4; ++mm) {
        const int gm0 = m0 + wr * 64 + mm * 16 + lr;
#pragma unroll
        for (int nn = 0; nn < 4; ++nn) {
            const int gn = n0 + wc * 64 + nn * 16 + lc;
            if (MODE == 4) {
                if (gn < 1536) {
                    const float bv = (gn < 768) ? bias[gn] : bias2[gn - 768];
                    unsigned short* o = (gn < 768) ? (unsigned short*)outp : (unsigned short*)out2;
                    const int col = (gn < 768) ? gn : gn - 768;
#pragma unroll
                    for (int r = 0; r < 4; ++r)
                        o[(size_t)(gm0 + r) * 768 + col] = f2bf(acc[mm][nn][r] + bv);
                } else {
                    const float bv = bias3[gn - 1536];
                    const int b = gm0 / T_;
                    const int tl = gm0 - b * T_;
                    us4 pk;
#pragma unroll
                    for (int r = 0; r < 4; ++r) pk[r] = f2bf(acc[mm][nn][r] + bv);
                    *(us4*)((unsigned short*)out3 + ((size_t)(b * D_ + gn - 1536)) * T_ + tl) = pk;
                }
            } else if (MODE == 5) {
                unsigned short* o = (unsigned short*)outp + (size_t)ks * partStride;
#pragma unroll
                for (int r = 0; r < 4; ++r)
                    o[(size_t)(gm0 + r) * N + gn] = f2bf(acc[mm][nn][r]);
            } else {
                const float bv = bias[gn];
#pragma unroll
                for (int r = 0; r < 4; ++r) {
                    const int gm = gm0 + r;
                    float v = acc[mm][nn][r] + bv;
                    if (MODE == 0) {
                        ((unsigned short*)outp)[(size_t)gm * N + gn] = f2bf(v);
                    } else if (MODE == 2) {
                        v = 0.5f * v * (1.0f + erff(v * 0.70710678118654752f));
                        ((unsigned short*)outp)[(size_t)gm * N + gn] = f2bf(v);
                    }
                }
            }
        }
    }
}

// ---------------- banded flash attention ----------------
// block = 256 threads (4 waves), handles (b, h, 64-query tile)
// K/V window = [t0, t1), KW <= 192
__global__ __launch_bounds__(256) void attn_kernel(
    const unsigned short* __restrict__ Q,    // [B*T][768]
    const unsigned short* __restrict__ Kg,   // [B*T][768]
    const unsigned short* __restrict__ Vt,   // [B][768][T]
    unsigned short* __restrict__ ctx)        // [B*T][768]
{
    __shared__ __align__(16) unsigned short Qs[64][72];
    __shared__ __align__(16) unsigned short KP[192 * 72];   // Ks, later Ps[64][200]
    __shared__ __align__(16) unsigned short Vts[64][200];

    const int tid = threadIdx.x;
    const int lane = tid & 63;
    const int w = tid >> 6;
    const int bid = blockIdx.x;
    const int qt = bid & 31;
    const int h = (bid >> 5) % H_;
    const int b = bid / (32 * H_);
    const int qs = qt * 64;
    const int t0 = qs >= 64 ? qs - 64 : 0;
    const int t1 = (qs + 128 < T_) ? qs + 128 : T_;
    const int KW = t1 - t0;

    for (int s = tid; s < 512; s += 256) {
        const int r = s >> 3, c8 = (s & 7) << 3;
        *(uint4*)&Qs[r][c8] =
            *(const uint4*)&Q[((size_t)(b * T_ + qs + r)) * D_ + h * DH_ + c8];
    }
    unsigned short* Ks = KP;
    for (int s = tid; s < 1536; s += 256) {
        const int r = s >> 3, c8 = (s & 7) << 3;
        uint4 val = {0, 0, 0, 0};
        if (r < KW)
            val = *(const uint4*)&Kg[((size_t)(b * T_ + t0 + r)) * D_ + h * DH_ + c8];
        *(uint4*)&Ks[r * 72 + c8] = val;
    }
    for (int s = tid; s < 1536; s += 256) {
        const int r = s / 24, c8 = (s % 24) << 3;
        uint4 val = {0, 0, 0, 0};
        if (c8 < KW)
            val = *(const uint4*)&Vt[((size_t)((b * H_ + h) * DH_ + r)) * T_ + t0 + c8];
        *(uint4*)&Vts[r][c8] = val;
    }
    __syncthreads();

    f32x4 zero4 = {0.0f, 0.0f, 0.0f, 0.0f};
    f32x4 sa[12];
#pragma unroll
    for (int i = 0; i < 12; ++i) sa[i] = zero4;
#pragma unroll
    for (int ks = 0; ks < 2; ++ks) {
        const bf16x8 aq = *(const bf16x8*)&Qs[w * 16 + (lane & 15)][ks * 32 + (lane >> 4) * 8];
#pragma unroll
        for (int cf = 0; cf < 12; ++cf) {
            const bf16x8 bk = *(const bf16x8*)&Ks[(cf * 16 + (lane & 15)) * 72 + ks * 32 + (lane >> 4) * 8];
            sa[cf] = MFMA16(aq, bk, sa[cf]);
        }
    }
    __syncthreads();

    const int lq = w * 16 + (lane >> 4) * 4;
    float mx[4] = {-1e30f, -1e30f, -1e30f, -1e30f};
#pragma unroll
    for (int cf = 0; cf < 12; ++cf) {
        const int key = t0 + cf * 16 + (lane & 15);
#pragma unroll
        for (int r = 0; r < 4; ++r) {
            const int dd = (qs + lq + r) - key;
            const bool ok = (key < t1) && (dd <= 64) && (dd >= -64);
            const float sv = ok ? sa[cf][r] * 0.125f : -1e30f;
            sa[cf][r] = sv;
            mx[r] = fmaxf(mx[r], sv);
        }
    }
#pragma unroll
    for (int r = 0; r < 4; ++r)
#pragma unroll
        for (int o = 1; o < 16; o <<= 1)
            mx[r] = fmaxf(mx[r], __shfl_xor(mx[r], o));

    unsigned short* Ps = KP;
    float sm[4] = {0.0f, 0.0f, 0.0f, 0.0f};
#pragma unroll
    for (int cf = 0; cf < 12; ++cf) {
#pragma unroll
        for (int r = 0; r < 4; ++r) {
            const float p = __expf(sa[cf][r] - mx[r]);
            sm[r] += p;
            Ps[(lq + r) * 200 + cf * 16 + (lane & 15)] = f2bf(p);
        }
    }
#pragma unroll
    for (int r = 0; r < 4; ++r)
#pragma unroll
        for (int o = 1; o < 16; o <<= 1)
            sm[r] += __shfl_xor(sm[r], o);

    f32x4 oa[4];
#pragma unroll
    for (int i = 0; i < 4; ++i) oa[i] = zero4;
#pragma unroll
    for (int ks = 0; ks < 6; ++ks) {
        const bf16x8 ap = *(const bf16x8*)&Ps[(w * 16 + (lane & 15)) * 200 + ks * 32 + (lane >> 4) * 8];
#pragma unroll
        for (int nf = 0; nf < 4; ++nf) {
            const bf16x8 bv = *(const bf16x8*)&Vts[nf * 16 + (lane & 15)][ks * 32 + (lane >> 4) * 8];
            oa[nf] = MFMA16(ap, bv, oa[nf]);
        }
    }
#pragma unroll
    for (int nf = 0; nf < 4; ++nf) {
#pragma unroll
        for (int r = 0; r < 4; ++r) {
            const float o = oa[nf][r] / sm[r];
            ctx[((size_t)(b * T_ + qs + lq + r)) * D_ + h * DH_ + nf * 16 + (lane & 15)] = f2bf(o);
        }
    }
}

// ---------------- orchestration ----------------
extern "C" void kernel_launch(void* const* d_in, const int* in_sizes, int n_in,
                              void* d_out, int out_size, void* d_ws, size_t ws_size,
                              hipStream_t stream)
{
    const float* x   = (const float*)d_in[0];
    const float* Wq  = (const float*)d_in[1];
    const float* bq  = (const float*)d_in[2];
    const float* Wk  = (const float*)d_in[3];
    const float* bk  = (const float*)d_in[4];
    const float* Wv  = (const float*)d_in[5];
    const float* bv  = (const float*)d_in[6];
    const float* Wo  = (const float*)d_in[7];
    const float* bo  = (const float*)d_in[8];
    const float* W1  = (const float*)d_in[9];
    const float* b1  = (const float*)d_in[10];
    const float* W2  = (const float*)d_in[11];
    const float* b2  = (const float*)d_in[12];
    const float* g1  = (const float*)d_in[13];
    const float* be1 = (const float*)d_in[14];
    const float* g2  = (const float*)d_in[15];
    const float* be2 = (const float*)d_in[16];
    float* out = (float*)d_out;

    unsigned short* wqkv_t = (unsigned short*)d_ws;        // 3 x [768][768]
    unsigned short* wo_t = wqkv_t + 3 * 589824;
    unsigned short* w1_t = wo_t + 589824;                  // [3072][768]
    unsigned short* w2_t = w1_t + 2359296;                 // [768][3072]
    unsigned short* hbuf = w2_t + 2359296;                 // h1, ctx, FF2-partials
    unsigned short* qbuf = hbuf + 6291456;                 // q, h2, FF2-partial hi
    float* x2 = (float*)(qbuf + 6291456);                  // fp32 [8192][768]
    unsigned short* kbuf = (unsigned short*)(x2 + 6291456); // k, Wo-partials
    unsigned short* vtb  = kbuf + 6291456;                 // [4][768][2048], Wo-partial hi
    unsigned short* ffb  = kbuf;                           // [8192][3072]

    dim3 tb(32, 8);
    tcvt4_kernel<<<dim3(24, 24, 4), tb, 0, stream>>>(Wq, Wk, Wv, Wo, wqkv_t);
    tcvt_kernel<<<dim3(96, 24), tb, 0, stream>>>(W1, w1_t, 768, 3072);
    tcvt_kernel<<<dim3(24, 96), tb, 0, stream>>>(W2, w2_t, 3072, 768);

    ln_kernel<<<8192, 256, 0, stream>>>(x, g1, be1, hbuf);

    // fused QKV: N = 2304, routes Q->qbuf, K->kbuf, V->vtb(transposed)
    gemm4w<4><<<64 * 18, 256, 0, stream>>>(
        hbuf, wqkv_t, bq, bk, bv, qbuf, kbuf, vtb, 2304, 768, 768, 18, 64 * 18, 0);

    attn_kernel<<<1536, 256, 0, stream>>>(qbuf, kbuf, vtb, hbuf);   // ctx -> hbuf

    // Wo: split-K S=2 (K'=384), bf16 partials into dead kbuf/vtb region
    gemm4w<5><<<64 * 6 * 2, 256, 0, stream>>>(
        hbuf, wo_t, nullptr, nullptr, nullptr, kbuf, nullptr, nullptr,
        768, 768, 384, 6, 64 * 6, 6291456);

    // fused reduce + residual + LN2: x2 (fp32) and h2 (bf16 -> qbuf)
    reduce_ln_kernel<<<8192, 256, 0, stream>>>(
        kbuf, kbuf + 6291456, x, bo, g2, be2, x2, qbuf);

    // FF1: gelu -> ffb (overwrites dead Wo partials)
    gemm4w<2><<<64 * 24, 256, 0, stream>>>(
        qbuf, w1_t, b1, nullptr, nullptr, ffb, nullptr, nullptr,
        3072, 768, 768, 24, 64 * 24, 0);

    // FF2: split-K S=2 (K'=1536), bf16 partials into dead hbuf/qbuf region
    gemm4w<5><<<64 * 6 * 2, 256, 0, stream>>>(
        ffb, w2_t, nullptr, nullptr, nullptr, hbuf, nullptr, nullptr,
        768, 3072, 1536, 6, 64 * 6, 6291456);

    reduce_out_kernel<<<2048, 256, 0, stream>>>(
        hbuf, hbuf + 6291456, x2, b2, out);
}

// Round 10
// 230.744 us; speedup vs baseline: 1.1414x; 1.0355x over previous
//
#include <hip/hip_runtime.h>
#include <hip/hip_bf16.h>

#define B_  4
#define T_  2048
#define D_  768
#define H_  12
#define DH_ 64
#define FF_ 3072

typedef __attribute__((ext_vector_type(8))) short bf16x8;
typedef __attribute__((ext_vector_type(4))) float f32x4;
typedef __attribute__((ext_vector_type(4))) unsigned short us4;

#define MFMA16(a, b, c) __builtin_amdgcn_mfma_f32_16x16x32_bf16((a), (b), (c), 0, 0, 0)

__device__ __forceinline__ unsigned short f2bf(float f) {
    union { float f; unsigned u; } v; v.f = f;
    unsigned r = v.u + 0x7fffu + ((v.u >> 16) & 1u);
    return (unsigned short)(r >> 16);
}
__device__ __forceinline__ float bf2f(unsigned short s) {
    union { unsigned u; float f; } v; v.u = ((unsigned)s) << 16;
    return v.f;
}

// cheap GELU: tanh form, |err vs exact| <= ~2e-4 (invisible at bf16 + W2 smear)
__device__ __forceinline__ float gelu_fast(float v) {
    const float u2 = 2.0f * v * fmaf(0.0356774081f, v * v, 0.7978845608f);
    const float e = __expf(u2);                      // e^(2u)
    const float r = __builtin_amdgcn_rcpf(e + 1.0f); // 1/(e+1)
    const float th = fmaf(-2.0f, r, 1.0f);           // tanh(u)
    return 0.5f * v * (1.0f + th);
}

// async global->LDS, 16B per lane. LDS dest must be wave-uniform; HW adds lane*16.
__device__ __forceinline__ void gload_lds16(const unsigned short* gp, unsigned short* lp) {
    __builtin_amdgcn_global_load_lds(
        (const __attribute__((address_space(1))) unsigned int*)gp,
        (__attribute__((address_space(3))) unsigned int*)lp,
        16, 0, 0);
}

// ---------------- weight convert + transpose: src[K][N] f32 -> dst[N][K] bf16 ----------
__global__ __launch_bounds__(256) void tcvt_kernel(
    const float* __restrict__ src, unsigned short* __restrict__ dst, int K, int N)
{
    __shared__ float tile[32][33];
    const int bx = blockIdx.x * 32;  // N dim
    const int by = blockIdx.y * 32;  // K dim
    const int tx = threadIdx.x, ty = threadIdx.y;  // 32 x 8
#pragma unroll
    for (int i = 0; i < 32; i += 8)
        tile[ty + i][tx] = src[(size_t)(by + ty + i) * N + bx + tx];
    __syncthreads();
#pragma unroll
    for (int i = 0; i < 32; i += 8)
        dst[(size_t)(bx + ty + i) * K + by + tx] = f2bf(tile[tx][ty + i]);
}

// batched version for the four 768x768 weights (Wq,Wk,Wv,Wo -> contiguous dst)
__global__ __launch_bounds__(256) void tcvt4_kernel(
    const float* __restrict__ s0, const float* __restrict__ s1,
    const float* __restrict__ s2, const float* __restrict__ s3,
    unsigned short* __restrict__ dst)
{
    __shared__ float tile[32][33];
    const int z = blockIdx.z;
    const float* src = (z == 0) ? s0 : (z == 1) ? s1 : (z == 2) ? s2 : s3;
    unsigned short* d = dst + (size_t)z * 589824;
    const int bx = blockIdx.x * 32;
    const int by = blockIdx.y * 32;
    const int tx = threadIdx.x, ty = threadIdx.y;
#pragma unroll
    for (int i = 0; i < 32; i += 8)
        tile[ty + i][tx] = src[(size_t)(by + ty + i) * 768 + bx + tx];
    __syncthreads();
#pragma unroll
    for (int i = 0; i < 32; i += 8)
        d[(size_t)(bx + ty + i) * 768 + by + tx] = f2bf(tile[tx][ty + i]);
}

// ---------------- LayerNorm: fp32 in -> bf16 out ----------------
// 4 rows per block, one wave per row; float4 loads, ushort4 stores,
// wave-only shuffle reduce (no LDS, no barrier).
__global__ __launch_bounds__(256) void ln_kernel(
    const float* __restrict__ x, const float* __restrict__ g,
    const float* __restrict__ be, unsigned short* __restrict__ out)
{
    const int lane = threadIdx.x & 63;
    const int row = blockIdx.x * 4 + (threadIdx.x >> 6);
    const float4* xr = (const float4*)(x + (size_t)row * D_);   // 192 float4
    float4 v0 = xr[lane], v1 = xr[lane + 64], v2 = xr[lane + 128];
    float s  = v0.x + v0.y + v0.z + v0.w + v1.x + v1.y + v1.z + v1.w
             + v2.x + v2.y + v2.z + v2.w;
    float s2 = v0.x*v0.x + v0.y*v0.y + v0.z*v0.z + v0.w*v0.w
             + v1.x*v1.x + v1.y*v1.y + v1.z*v1.z + v1.w*v1.w
             + v2.x*v2.x + v2.y*v2.y + v2.z*v2.z + v2.w*v2.w;
#pragma unroll
    for (int o = 1; o < 64; o <<= 1) {
        s  += __shfl_xor(s,  o);
        s2 += __shfl_xor(s2, o);
    }
    const float mu = s * (1.0f / D_);
    const float var = s2 * (1.0f / D_) - mu * mu;
    const float rstd = rsqrtf(var + 1e-5f);
    const float4* gv = (const float4*)g;
    const float4* bv = (const float4*)be;
    us4* orow = (us4*)(out + (size_t)row * D_);
#pragma unroll
    for (int k = 0; k < 3; ++k) {
        const float4 v = (k == 0) ? v0 : (k == 1) ? v1 : v2;
        const float4 gg = gv[lane + k * 64];
        const float4 bb = bv[lane + k * 64];
        us4 p;
        p[0] = f2bf((v.x - mu) * rstd * gg.x + bb.x);
        p[1] = f2bf((v.y - mu) * rstd * gg.y + bb.y);
        p[2] = f2bf((v.z - mu) * rstd * gg.z + bb.z);
        p[3] = f2bf((v.w - mu) * rstd * gg.w + bb.w);
        orow[lane + k * 64] = p;
    }
}

// ---- fused split-K reduce + residual + LayerNorm (Wo path) ----
__global__ __launch_bounds__(256) void reduce_ln_kernel(
    const unsigned short* __restrict__ p0, const unsigned short* __restrict__ p1,
    const float* __restrict__ x, const float* __restrict__ bo,
    const float* __restrict__ g, const float* __restrict__ be,
    float* __restrict__ x2, unsigned short* __restrict__ h2)
{
    const int row = blockIdx.x;
    const int t = threadIdx.x;
    const size_t base = (size_t)row * D_;
    float v[3];
    float s = 0.0f, s2 = 0.0f;
#pragma unroll
    for (int j = 0; j < 3; ++j) {
        const int c = t + j * 256;
        const float vv = bf2f(p0[base + c]) + bf2f(p1[base + c]) + bo[c] + x[base + c];
        v[j] = vv;
        x2[base + c] = vv;
        s += vv; s2 += vv * vv;
    }
#pragma unroll
    for (int o = 1; o < 64; o <<= 1) {
        s  += __shfl_xor(s,  o);
        s2 += __shfl_xor(s2, o);
    }
    __shared__ float rs[4], rq[4];
    const int wave = t >> 6;
    if ((t & 63) == 0) { rs[wave] = s; rq[wave] = s2; }
    __syncthreads();
    s  = rs[0] + rs[1] + rs[2] + rs[3];
    s2 = rq[0] + rq[1] + rq[2] + rq[3];
    const float mu = s * (1.0f / D_);
    const float var = s2 * (1.0f / D_) - mu * mu;
    const float rstd = rsqrtf(var + 1e-5f);
#pragma unroll
    for (int j = 0; j < 3; ++j) {
        const int c = t + j * 256;
        h2[base + c] = f2bf((v[j] - mu) * rstd * g[c] + be[c]);
    }
}

// ---- split-K reduce + bias + residual (FF2 path, fp32 out) ----
__global__ __launch_bounds__(256) void reduce_out_kernel(
    const unsigned short* __restrict__ p0, const unsigned short* __restrict__ p1,
    const float* __restrict__ x2, const float* __restrict__ b2,
    float* __restrict__ out)
{
    const int n4 = B_ * T_ * D_ / 4;
    for (int i = blockIdx.x * 256 + threadIdx.x; i < n4; i += gridDim.x * 256) {
        const us4 a = ((const us4*)p0)[i];
        const us4 b = ((const us4*)p1)[i];
        const float4 xr = ((const float4*)x2)[i];
        const int col = (i * 4) % D_;
        float4 o;
        o.x = bf2f(a[0]) + bf2f(b[0]) + b2[col]     + xr.x;
        o.y = bf2f(a[1]) + bf2f(b[1]) + b2[col + 1] + xr.y;
        o.z = bf2f(a[2]) + bf2f(b[2]) + b2[col + 2] + xr.z;
        o.w = bf2f(a[3]) + bf2f(b[3]) + b2[col + 3] + xr.w;
        ((float4*)out)[i] = o;
    }
}

// ---------------- 4-wave m97-structure GEMM: C = A[M][K] * Bt[N][K]^T ----------------
// BM=BN=128, BK=64; 256 threads (4 waves 2x2), wave-tile 64x64 (acc 4x4).
// LDS 32KB, ~3 blocks/CU co-residency hides latency. LDS rows = 64 shorts =
// 8 x 16B blocks; block b of row r at b^(r&7) via pre-swizzled global SOURCE
// (gload dest linear); ds_read same XOR -> measured 0 bank conflicts.
// 1D grid over (ks, mTile, nTile), N-fastest; bijective XCD swizzle.
// Split-K: ks = swz / nTilesMN, K range [ks*kLen, (ks+1)*kLen).
// MODE 0: bf16 out; MODE 2: gelu_fast->bf16; MODE 4: fused QKV routing;
// MODE 5: bf16 partial at outp + ks*partStride (no bias).
template<int MODE>
__global__ __launch_bounds__(256, 3) void gemm4w(
    const unsigned short* __restrict__ A,
    const unsigned short* __restrict__ Bt,
    const float* __restrict__ bias,
    const float* __restrict__ bias2,
    const float* __restrict__ bias3,
    void* __restrict__ outp,
    void* __restrict__ out2,
    void* __restrict__ out3,
    int N, int K, int kLen, int nTilesN, int nTilesMN, long partStride)
{
    __shared__ __align__(16) unsigned short As[128 * 64];
    __shared__ __align__(16) unsigned short Bs[128 * 64];

    // bijective XCD swizzle (m204)
    const int nwg = gridDim.x;
    const int q = nwg >> 3, rr = nwg & 7;
    const int xcd = blockIdx.x & 7, loc = blockIdx.x >> 3;
    const int swz = (xcd < rr ? xcd * (q + 1) : rr * (q + 1) + (xcd - rr) * q) + loc;
    const int ks  = swz / nTilesMN;
    const int rem = swz - ks * nTilesMN;
    const int m0 = (rem / nTilesN) * 128;
    const int n0 = (rem % nTilesN) * 128;
    const int kOff = ks * kLen;

    const int tid = threadIdx.x;
    const int wv = tid >> 6;
    const int lane = tid & 63;
    const int wr = wv >> 1;          // 0..1 (M)
    const int wc = wv & 1;           // 0..1 (N)

    f32x4 zero4 = {0.0f, 0.0f, 0.0f, 0.0f};
    f32x4 acc[4][4];
#pragma unroll
    for (int i = 0; i < 4; ++i)
#pragma unroll
        for (int j = 0; j < 4; ++j) acc[i][j] = zero4;

    // staging: each wave stages 32 rows of A and 32 rows of B (4 chunks of
    // 8 rows x 64 shorts each). lane -> (lrow=lane>>3, blk=lane&7);
    // source col-block = blk ^ lrow (chunk bases are multiples of 8 rows).
    const int lrow = lane >> 3;
    const int scb = (lane & 7) ^ lrow;
    const unsigned short* ag = A  + (size_t)(m0 + wv * 32 + lrow) * K + kOff + scb * 8;
    const unsigned short* bg = Bt + (size_t)(n0 + wv * 32 + lrow) * K + kOff + scb * 8;
    unsigned short* aLds = As + wv * 32 * 64;
    unsigned short* bLds = Bs + wv * 32 * 64;

    // fragment-read setup
    const int fr = lane & 15;
    const int fg = lane >> 4;        // 0..3
    const int sw = fr & 7;
    const int aRow = (wr * 64 + fr) * 64;   // + mm*16*64
    const int bRow = (wc * 64 + fr) * 64;   // + nn*16*64

    const int nk = kLen >> 6;
    for (int kt = 0; kt < nk; ++kt) {
        const int k0 = kt << 6;
        __syncthreads();
#pragma unroll
        for (int c = 0; c < 4; ++c)
            gload_lds16(ag + k0 + (size_t)c * 8 * K, aLds + c * 512);
#pragma unroll
        for (int c = 0; c < 4; ++c)
            gload_lds16(bg + k0 + (size_t)c * 8 * K, bLds + c * 512);
        __syncthreads();

#pragma unroll
        for (int kk = 0; kk < 2; ++kk) {
            bf16x8 afr[4], bfr[4];
            const int cb = ((kk * 4 + fg) ^ sw) << 3;
#pragma unroll
            for (int mm = 0; mm < 4; ++mm)
                afr[mm] = *(const bf16x8*)(As + aRow + mm * 1024 + cb);
#pragma unroll
            for (int nn = 0; nn < 4; ++nn)
                bfr[nn] = *(const bf16x8*)(Bs + bRow + nn * 1024 + cb);
#pragma unroll
            for (int mm = 0; mm < 4; ++mm)
#pragma unroll
                for (int nn = 0; nn < 4; ++nn)
                    acc[mm][nn] = MFMA16(afr[mm], bfr[nn], acc[mm][nn]);
        }
    }

    // ---- epilogue
    const int lc = lane & 15;
    const int lr = (lane >> 4) * 4;
#pragma unroll
    for (int mm = 0; mm < 4; ++mm) {
        const int gm0 = m0 + wr * 64 + mm * 16 + lr;
#pragma unroll
        for (int nn = 0; nn < 4; ++nn) {
            const int gn = n0 + wc * 64 + nn * 16 + lc;
            if (MODE == 4) {
                if (gn < 1536) {
                    const float bv = (gn < 768) ? bias[gn] : bias2[gn - 768];
                    unsigned short* o = (gn < 768) ? (unsigned short*)outp : (unsigned short*)out2;
                    const int col = (gn < 768) ? gn : gn - 768;
#pragma unroll
                    for (int r = 0; r < 4; ++r)
                        o[(size_t)(gm0 + r) * 768 + col] = f2bf(acc[mm][nn][r] + bv);
                } else {
                    const float bv = bias3[gn - 1536];
                    const int b = gm0 / T_;
                    const int tl = gm0 - b * T_;
                    us4 pk;
#pragma unroll
                    for (int r = 0; r < 4; ++r) pk[r] = f2bf(acc[mm][nn][r] + bv);
                    *(us4*)((unsigned short*)out3 + ((size_t)(b * D_ + gn - 1536)) * T_ + tl) = pk;
                }
            } else if (MODE == 5) {
                unsigned short* o = (unsigned short*)outp + (size_t)ks * partStride;
#pragma unroll
                for (int r = 0; r < 4; ++r)
                    o[(size_t)(gm0 + r) * N + gn] = f2bf(acc[mm][nn][r]);
            } else {
                const float bv = bias[gn];
#pragma unroll
                for (int r = 0; r < 4; ++r) {
                    const int gm = gm0 + r;
                    float v = acc[mm][nn][r] + bv;
                    if (MODE == 0) {
                        ((unsigned short*)outp)[(size_t)gm * N + gn] = f2bf(v);
                    } else if (MODE == 2) {
                        ((unsigned short*)outp)[(size_t)gm * N + gn] = f2bf(gelu_fast(v));
                    }
                }
            }
        }
    }
}

// ---------------- banded flash attention ----------------
// block = 256 threads (4 waves), handles (b, h, 64-query tile)
// K/V window = [t0, t1), KW <= 192
__global__ __launch_bounds__(256) void attn_kernel(
    const unsigned short* __restrict__ Q,    // [B*T][768]
    const unsigned short* __restrict__ Kg,   // [B*T][768]
    const unsigned short* __restrict__ Vt,   // [B][768][T]
    unsigned short* __restrict__ ctx)        // [B*T][768]
{
    __shared__ __align__(16) unsigned short Qs[64][72];
    __shared__ __align__(16) unsigned short KP[192 * 72];   // Ks, later Ps[64][200]
    __shared__ __align__(16) unsigned short Vts[64][200];

    const int tid = threadIdx.x;
    const int lane = tid & 63;
    const int w = tid >> 6;
    const int bid = blockIdx.x;
    const int qt = bid & 31;
    const int h = (bid >> 5) % H_;
    const int b = bid / (32 * H_);
    const int qs = qt * 64;
    const int t0 = qs >= 64 ? qs - 64 : 0;
    const int t1 = (qs + 128 < T_) ? qs + 128 : T_;
    const int KW = t1 - t0;

    for (int s = tid; s < 512; s += 256) {
        const int r = s >> 3, c8 = (s & 7) << 3;
        *(uint4*)&Qs[r][c8] =
            *(const uint4*)&Q[((size_t)(b * T_ + qs + r)) * D_ + h * DH_ + c8];
    }
    unsigned short* Ks = KP;
    for (int s = tid; s < 1536; s += 256) {
        const int r = s >> 3, c8 = (s & 7) << 3;
        uint4 val = {0, 0, 0, 0};
        if (r < KW)
            val = *(const uint4*)&Kg[((size_t)(b * T_ + t0 + r)) * D_ + h * DH_ + c8];
        *(uint4*)&Ks[r * 72 + c8] = val;
    }
    for (int s = tid; s < 1536; s += 256) {
        const int r = s / 24, c8 = (s % 24) << 3;
        uint4 val = {0, 0, 0, 0};
        if (c8 < KW)
            val = *(const uint4*)&Vt[((size_t)((b * H_ + h) * DH_ + r)) * T_ + t0 + c8];
        *(uint4*)&Vts[r][c8] = val;
    }
    __syncthreads();

    f32x4 zero4 = {0.0f, 0.0f, 0.0f, 0.0f};
    f32x4 sa[12];
#pragma unroll
    for (int i = 0; i < 12; ++i) sa[i] = zero4;
#pragma unroll
    for (int ks = 0; ks < 2; ++ks) {
        const bf16x8 aq = *(const bf16x8*)&Qs[w * 16 + (lane & 15)][ks * 32 + (lane >> 4) * 8];
#pragma unroll
        for (int cf = 0; cf < 12; ++cf) {
            const bf16x8 bk = *(const bf16x8*)&Ks[(cf * 16 + (lane & 15)) * 72 + ks * 32 + (lane >> 4) * 8];
            sa[cf] = MFMA16(aq, bk, sa[cf]);
        }
    }
    __syncthreads();

    const int lq = w * 16 + (lane >> 4) * 4;
    float mx[4] = {-1e30f, -1e30f, -1e30f, -1e30f};
#pragma unroll
    for (int cf = 0; cf < 12; ++cf) {
        const int key = t0 + cf * 16 + (lane & 15);
#pragma unroll
        for (int r = 0; r < 4; ++r) {
            const int dd = (qs + lq + r) - key;
            const bool ok = (key < t1) && (dd <= 64) && (dd >= -64);
            const float sv = ok ? sa[cf][r] * 0.125f : -1e30f;
            sa[cf][r] = sv;
            mx[r] = fmaxf(mx[r], sv);
        }
    }
#pragma unroll
    for (int r = 0; r < 4; ++r)
#pragma unroll
        for (int o = 1; o < 16; o <<= 1)
            mx[r] = fmaxf(mx[r], __shfl_xor(mx[r], o));

    unsigned short* Ps = KP;
    float sm[4] = {0.0f, 0.0f, 0.0f, 0.0f};
#pragma unroll
    for (int cf = 0; cf < 12; ++cf) {
#pragma unroll
        for (int r = 0; r < 4; ++r) {
            const float p = __expf(sa[cf][r] - mx[r]);
            sm[r] += p;
            Ps[(lq + r) * 200 + cf * 16 + (lane & 15)] = f2bf(p);
        }
    }
#pragma unroll
    for (int r = 0; r < 4; ++r)
#pragma unroll
        for (int o = 1; o < 16; o <<= 1)
            sm[r] += __shfl_xor(sm[r], o);

    f32x4 oa[4];
#pragma unroll
    for (int i = 0; i < 4; ++i) oa[i] = zero4;
#pragma unroll
    for (int ks = 0; ks < 6; ++ks) {
        const bf16x8 ap = *(const bf16x8*)&Ps[(w * 16 + (lane & 15)) * 200 + ks * 32 + (lane >> 4) * 8];
#pragma unroll
        for (int nf = 0; nf < 4; ++nf) {
            const bf16x8 bv = *(const bf16x8*)&Vts[nf * 16 + (lane & 15)][ks * 32 + (lane >> 4) * 8];
            oa[nf] = MFMA16(ap, bv, oa[nf]);
        }
    }
#pragma unroll
    for (int nf = 0; nf < 4; ++nf) {
#pragma unroll
        for (int r = 0; r < 4; ++r) {
            const float o = oa[nf][r] / sm[r];
            ctx[((size_t)(b * T_ + qs + lq + r)) * D_ + h * DH_ + nf * 16 + (lane & 15)] = f2bf(o);
        }
    }
}

// ---------------- orchestration ----------------
extern "C" void kernel_launch(void* const* d_in, const int* in_sizes, int n_in,
                              void* d_out, int out_size, void* d_ws, size_t ws_size,
                              hipStream_t stream)
{
    const float* x   = (const float*)d_in[0];
    const float* Wq  = (const float*)d_in[1];
    const float* bq  = (const float*)d_in[2];
    const float* Wk  = (const float*)d_in[3];
    const float* bk  = (const float*)d_in[4];
    const float* Wv  = (const float*)d_in[5];
    const float* bv  = (const float*)d_in[6];
    const float* Wo  = (const float*)d_in[7];
    const float* bo  = (const float*)d_in[8];
    const float* W1  = (const float*)d_in[9];
    const float* b1  = (const float*)d_in[10];
    const float* W2  = (const float*)d_in[11];
    const float* b2  = (const float*)d_in[12];
    const float* g1  = (const float*)d_in[13];
    const float* be1 = (const float*)d_in[14];
    const float* g2  = (const float*)d_in[15];
    const float* be2 = (const float*)d_in[16];
    float* out = (float*)d_out;

    unsigned short* wqkv_t = (unsigned short*)d_ws;        // 3 x [768][768]
    unsigned short* wo_t = wqkv_t + 3 * 589824;
    unsigned short* w1_t = wo_t + 589824;                  // [3072][768]
    unsigned short* w2_t = w1_t + 2359296;                 // [768][3072]
    unsigned short* hbuf = w2_t + 2359296;                 // h1, ctx, FF2-partials
    unsigned short* qbuf = hbuf + 6291456;                 // q, h2, FF2-partial hi
    float* x2 = (float*)(qbuf + 6291456);                  // fp32 [8192][768]
    unsigned short* kbuf = (unsigned short*)(x2 + 6291456); // k, Wo-partials
    unsigned short* vtb  = kbuf + 6291456;                 // [4][768][2048], Wo-partial hi
    unsigned short* ffb  = kbuf;                           // [8192][3072]

    dim3 tb(32, 8);
    tcvt4_kernel<<<dim3(24, 24, 4), tb, 0, stream>>>(Wq, Wk, Wv, Wo, wqkv_t);
    tcvt_kernel<<<dim3(96, 24), tb, 0, stream>>>(W1, w1_t, 768, 3072);
    tcvt_kernel<<<dim3(24, 96), tb, 0, stream>>>(W2, w2_t, 3072, 768);

    ln_kernel<<<2048, 256, 0, stream>>>(x, g1, be1, hbuf);

    // fused QKV: N = 2304, routes Q->qbuf, K->kbuf, V->vtb(transposed)
    gemm4w<4><<<64 * 18, 256, 0, stream>>>(
        hbuf, wqkv_t, bq, bk, bv, qbuf, kbuf, vtb, 2304, 768, 768, 18, 64 * 18, 0);

    attn_kernel<<<1536, 256, 0, stream>>>(qbuf, kbuf, vtb, hbuf);   // ctx -> hbuf

    // Wo: split-K S=2 (K'=384), bf16 partials into dead kbuf/vtb region
    gemm4w<5><<<64 * 6 * 2, 256, 0, stream>>>(
        hbuf, wo_t, nullptr, nullptr, nullptr, kbuf, nullptr, nullptr,
        768, 768, 384, 6, 64 * 6, 6291456);

    // fused reduce + residual + LN2: x2 (fp32) and h2 (bf16 -> qbuf)
    reduce_ln_kernel<<<8192, 256, 0, stream>>>(
        kbuf, kbuf + 6291456, x, bo, g2, be2, x2, qbuf);

    // FF1: gelu_fast -> ffb (overwrites dead Wo partials)
    gemm4w<2><<<64 * 24, 256, 0, stream>>>(
        qbuf, w1_t, b1, nullptr, nullptr, ffb, nullptr, nullptr,
        3072, 768, 768, 24, 64 * 24, 0);

    // FF2: split-K S=2 (K'=1536), bf16 partials into dead hbuf/qbuf region
    gemm4w<5><<<64 * 6 * 2, 256, 0, stream>>>(
        ffb, w2_t, nullptr, nullptr, nullptr, hbuf, nullptr, nullptr,
        768, 3072, 1536, 6, 64 * 6, 6291456);

    reduce_out_kernel<<<2048, 256, 0, stream>>>(
        hbuf, hbuf + 6291456, x2, b2, out);
}

// Round 11
// 223.137 us; speedup vs baseline: 1.1803x; 1.0341x over previous
//
#include <hip/hip_runtime.h>
#include <hip/hip_bf16.h>

#define B_  4
#define T_  2048
#define D_  768
#define H_  12
#define DH_ 64
#define FF_ 3072

typedef __attribute__((ext_vector_type(8))) short bf16x8;
typedef __attribute__((ext_vector_type(4))) float f32x4;
typedef __attribute__((ext_vector_type(4))) unsigned short us4;
typedef __attribute__((ext_vector_type(8))) unsigned short us8;

#define MFMA16(a, b, c) __builtin_amdgcn_mfma_f32_16x16x32_bf16((a), (b), (c), 0, 0, 0)

__device__ __forceinline__ unsigned short f2bf(float f) {
    union { float f; unsigned u; } v; v.f = f;
    unsigned r = v.u + 0x7fffu + ((v.u >> 16) & 1u);
    return (unsigned short)(r >> 16);
}
__device__ __forceinline__ float bf2f(unsigned short s) {
    union { unsigned u; float f; } v; v.u = ((unsigned)s) << 16;
    return v.f;
}

// cheap GELU: tanh form, |err vs exact| <= ~2e-4 (invisible at bf16 + W2 smear)
__device__ __forceinline__ float gelu_fast(float v) {
    const float u2 = 2.0f * v * fmaf(0.0356774081f, v * v, 0.7978845608f);
    const float e = __expf(u2);                      // e^(2u)
    const float r = __builtin_amdgcn_rcpf(e + 1.0f); // 1/(e+1)
    const float th = fmaf(-2.0f, r, 1.0f);           // tanh(u)
    return 0.5f * v * (1.0f + th);
}

// async global->LDS, 16B per lane. LDS dest must be wave-uniform; HW adds lane*16.
__device__ __forceinline__ void gload_lds16(const unsigned short* gp, unsigned short* lp) {
    __builtin_amdgcn_global_load_lds(
        (const __attribute__((address_space(1))) unsigned int*)gp,
        (__attribute__((address_space(3))) unsigned int*)lp,
        16, 0, 0);
}

// ---------------- weight convert + transpose: src[K][N] f32 -> dst[N][K] bf16 ----------
__global__ __launch_bounds__(256) void tcvt_kernel(
    const float* __restrict__ src, unsigned short* __restrict__ dst, int K, int N)
{
    __shared__ float tile[32][33];
    const int bx = blockIdx.x * 32;  // N dim
    const int by = blockIdx.y * 32;  // K dim
    const int tx = threadIdx.x, ty = threadIdx.y;  // 32 x 8
#pragma unroll
    for (int i = 0; i < 32; i += 8)
        tile[ty + i][tx] = src[(size_t)(by + ty + i) * N + bx + tx];
    __syncthreads();
#pragma unroll
    for (int i = 0; i < 32; i += 8)
        dst[(size_t)(bx + ty + i) * K + by + tx] = f2bf(tile[tx][ty + i]);
}

// batched version for the four 768x768 weights (Wq,Wk,Wv,Wo -> contiguous dst)
__global__ __launch_bounds__(256) void tcvt4_kernel(
    const float* __restrict__ s0, const float* __restrict__ s1,
    const float* __restrict__ s2, const float* __restrict__ s3,
    unsigned short* __restrict__ dst)
{
    __shared__ float tile[32][33];
    const int z = blockIdx.z;
    const float* src = (z == 0) ? s0 : (z == 1) ? s1 : (z == 2) ? s2 : s3;
    unsigned short* d = dst + (size_t)z * 589824;
    const int bx = blockIdx.x * 32;
    const int by = blockIdx.y * 32;
    const int tx = threadIdx.x, ty = threadIdx.y;
#pragma unroll
    for (int i = 0; i < 32; i += 8)
        tile[ty + i][tx] = src[(size_t)(by + ty + i) * 768 + bx + tx];
    __syncthreads();
#pragma unroll
    for (int i = 0; i < 32; i += 8)
        d[(size_t)(bx + ty + i) * 768 + by + tx] = f2bf(tile[tx][ty + i]);
}

// ---------------- LayerNorm: fp32 in -> bf16 out ----------------
// 4 rows per block, one wave per row; float4 loads, ushort4 stores.
__global__ __launch_bounds__(256) void ln_kernel(
    const float* __restrict__ x, const float* __restrict__ g,
    const float* __restrict__ be, unsigned short* __restrict__ out)
{
    const int lane = threadIdx.x & 63;
    const int row = blockIdx.x * 4 + (threadIdx.x >> 6);
    const float4* xr = (const float4*)(x + (size_t)row * D_);   // 192 float4
    float4 v0 = xr[lane], v1 = xr[lane + 64], v2 = xr[lane + 128];
    float s  = v0.x + v0.y + v0.z + v0.w + v1.x + v1.y + v1.z + v1.w
             + v2.x + v2.y + v2.z + v2.w;
    float s2 = v0.x*v0.x + v0.y*v0.y + v0.z*v0.z + v0.w*v0.w
             + v1.x*v1.x + v1.y*v1.y + v1.z*v1.z + v1.w*v1.w
             + v2.x*v2.x + v2.y*v2.y + v2.z*v2.z + v2.w*v2.w;
#pragma unroll
    for (int o = 1; o < 64; o <<= 1) {
        s  += __shfl_xor(s,  o);
        s2 += __shfl_xor(s2, o);
    }
    const float mu = s * (1.0f / D_);
    const float var = s2 * (1.0f / D_) - mu * mu;
    const float rstd = rsqrtf(var + 1e-5f);
    const float4* gv = (const float4*)g;
    const float4* bv = (const float4*)be;
    us4* orow = (us4*)(out + (size_t)row * D_);
#pragma unroll
    for (int k = 0; k < 3; ++k) {
        const float4 v = (k == 0) ? v0 : (k == 1) ? v1 : v2;
        const float4 gg = gv[lane + k * 64];
        const float4 bb = bv[lane + k * 64];
        us4 p;
        p[0] = f2bf((v.x - mu) * rstd * gg.x + bb.x);
        p[1] = f2bf((v.y - mu) * rstd * gg.y + bb.y);
        p[2] = f2bf((v.z - mu) * rstd * gg.z + bb.z);
        p[3] = f2bf((v.w - mu) * rstd * gg.w + bb.w);
        orow[lane + k * 64] = p;
    }
}

// ---- fused split-K reduce + residual + LayerNorm (Wo path) ----
// x2 = p0 + p1 + bo + x (stored bf16); h2 = LN(x2)*g2+be2 (bf16).
// 4 rows/block, wave per row; all loads vectorized.
__global__ __launch_bounds__(256) void reduce_ln_kernel(
    const unsigned short* __restrict__ p0, const unsigned short* __restrict__ p1,
    const float* __restrict__ x, const float* __restrict__ bo,
    const float* __restrict__ g, const float* __restrict__ be,
    unsigned short* __restrict__ x2, unsigned short* __restrict__ h2)
{
    const int lane = threadIdx.x & 63;
    const int row = blockIdx.x * 4 + (threadIdx.x >> 6);
    const size_t base = (size_t)row * D_;
    float v[12];
    float s = 0.0f, s2 = 0.0f;
#pragma unroll
    for (int k = 0; k < 3; ++k) {
        const int c = k * 256 + lane * 4;
        const us4 a = *(const us4*)(p0 + base + c);
        const us4 b = *(const us4*)(p1 + base + c);
        const float4 xr = *(const float4*)(x + base + c);
        const float4 bb = *(const float4*)(bo + c);
        const float w0 = bf2f(a[0]) + bf2f(b[0]) + bb.x + xr.x;
        const float w1 = bf2f(a[1]) + bf2f(b[1]) + bb.y + xr.y;
        const float w2 = bf2f(a[2]) + bf2f(b[2]) + bb.z + xr.z;
        const float w3 = bf2f(a[3]) + bf2f(b[3]) + bb.w + xr.w;
        v[k * 4 + 0] = w0; v[k * 4 + 1] = w1; v[k * 4 + 2] = w2; v[k * 4 + 3] = w3;
        s += w0 + w1 + w2 + w3;
        s2 += w0 * w0 + w1 * w1 + w2 * w2 + w3 * w3;
    }
#pragma unroll
    for (int o = 1; o < 64; o <<= 1) {
        s  += __shfl_xor(s,  o);
        s2 += __shfl_xor(s2, o);
    }
    const float mu = s * (1.0f / D_);
    const float var = s2 * (1.0f / D_) - mu * mu;
    const float rstd = rsqrtf(var + 1e-5f);
#pragma unroll
    for (int k = 0; k < 3; ++k) {
        const int c = k * 256 + lane * 4;
        const float4 gg = *(const float4*)(g + c);
        const float4 bb = *(const float4*)(be + c);
        us4 xo, ho;
        xo[0] = f2bf(v[k*4+0]); xo[1] = f2bf(v[k*4+1]);
        xo[2] = f2bf(v[k*4+2]); xo[3] = f2bf(v[k*4+3]);
        ho[0] = f2bf((v[k*4+0] - mu) * rstd * gg.x + bb.x);
        ho[1] = f2bf((v[k*4+1] - mu) * rstd * gg.y + bb.y);
        ho[2] = f2bf((v[k*4+2] - mu) * rstd * gg.z + bb.z);
        ho[3] = f2bf((v[k*4+3] - mu) * rstd * gg.w + bb.w);
        *(us4*)(x2 + base + c) = xo;
        *(us4*)(h2 + base + c) = ho;
    }
}

// ---- split-K reduce + bias + residual (FF2 path, fp32 out; x2 bf16) ----
__global__ __launch_bounds__(256) void reduce_out_kernel(
    const unsigned short* __restrict__ p0, const unsigned short* __restrict__ p1,
    const unsigned short* __restrict__ x2, const float* __restrict__ b2,
    float* __restrict__ out)
{
    const int n4 = B_ * T_ * D_ / 4;
    for (int i = blockIdx.x * 256 + threadIdx.x; i < n4; i += gridDim.x * 256) {
        const us4 a = ((const us4*)p0)[i];
        const us4 b = ((const us4*)p1)[i];
        const us4 xr = ((const us4*)x2)[i];
        const int col = (i * 4) % D_;
        const float4 bb = *(const float4*)(b2 + col);
        float4 o;
        o.x = bf2f(a[0]) + bf2f(b[0]) + bb.x + bf2f(xr[0]);
        o.y = bf2f(a[1]) + bf2f(b[1]) + bb.y + bf2f(xr[1]);
        o.z = bf2f(a[2]) + bf2f(b[2]) + bb.z + bf2f(xr[2]);
        o.w = bf2f(a[3]) + bf2f(b[3]) + bb.w + bf2f(xr[3]);
        ((float4*)out)[i] = o;
    }
}

// ---------------- 4-wave m97-structure GEMM: C = A[M][K] * Bt[N][K]^T ----------------
// BM=BN=128, BK=64; 256 threads (4 waves 2x2), wave-tile 64x64 (acc 4x4).
// LDS 32KB, ~3 blocks/CU co-residency hides latency. LDS rows = 64 shorts =
// 8 x 16B blocks; block b of row r at b^(r&7) via pre-swizzled global SOURCE
// (gload dest linear); ds_read same XOR -> measured 0 bank conflicts.
// 1D grid over (ks, mTile, nTile), N-fastest; bijective XCD swizzle.
// MODE 0: bf16 out; MODE 2: gelu_fast->bf16; MODE 4: fused QKV routing
// (tile-uniform: n0<768 Q, <1536 K, else V via LDS-bounce transposed us8
//  stores -> full 128B lines, no L2 RMW); MODE 5: bf16 partial (split-K).
template<int MODE>
__global__ __launch_bounds__(256, 3) void gemm4w(
    const unsigned short* __restrict__ A,
    const unsigned short* __restrict__ Bt,
    const float* __restrict__ bias,
    const float* __restrict__ bias2,
    const float* __restrict__ bias3,
    void* __restrict__ outp,
    void* __restrict__ out2,
    void* __restrict__ out3,
    int N, int K, int kLen, int nTilesN, int nTilesMN, long partStride)
{
    __shared__ __align__(16) unsigned short As[128 * 64];
    __shared__ __align__(16) unsigned short Bs[128 * 64];

    // bijective XCD swizzle (m204)
    const int nwg = gridDim.x;
    const int q = nwg >> 3, rr = nwg & 7;
    const int xcd = blockIdx.x & 7, loc = blockIdx.x >> 3;
    const int swz = (xcd < rr ? xcd * (q + 1) : rr * (q + 1) + (xcd - rr) * q) + loc;
    const int ks  = swz / nTilesMN;
    const int rem = swz - ks * nTilesMN;
    const int m0 = (rem / nTilesN) * 128;
    const int n0 = (rem % nTilesN) * 128;
    const int kOff = ks * kLen;

    const int tid = threadIdx.x;
    const int wv = tid >> 6;
    const int lane = tid & 63;
    const int wr = wv >> 1;          // 0..1 (M)
    const int wc = wv & 1;           // 0..1 (N)

    f32x4 zero4 = {0.0f, 0.0f, 0.0f, 0.0f};
    f32x4 acc[4][4];
#pragma unroll
    for (int i = 0; i < 4; ++i)
#pragma unroll
        for (int j = 0; j < 4; ++j) acc[i][j] = zero4;

    // staging: each wave stages 32 rows of A and 32 rows of B (4 chunks of
    // 8 rows x 64 shorts each). lane -> (lrow=lane>>3, blk=lane&7);
    // source col-block = blk ^ lrow (chunk bases are multiples of 8 rows).
    const int lrow = lane >> 3;
    const int scb = (lane & 7) ^ lrow;
    const unsigned short* ag = A  + (size_t)(m0 + wv * 32 + lrow) * K + kOff + scb * 8;
    const unsigned short* bg = Bt + (size_t)(n0 + wv * 32 + lrow) * K + kOff + scb * 8;
    unsigned short* aLds = As + wv * 32 * 64;
    unsigned short* bLds = Bs + wv * 32 * 64;

    // fragment-read setup
    const int fr = lane & 15;
    const int fg = lane >> 4;        // 0..3
    const int sw = fr & 7;
    const int aRow = (wr * 64 + fr) * 64;   // + mm*16*64
    const int bRow = (wc * 64 + fr) * 64;   // + nn*16*64

    const int nk = kLen >> 6;
    for (int kt = 0; kt < nk; ++kt) {
        const int k0 = kt << 6;
        __syncthreads();
#pragma unroll
        for (int c = 0; c < 4; ++c)
            gload_lds16(ag + k0 + (size_t)c * 8 * K, aLds + c * 512);
#pragma unroll
        for (int c = 0; c < 4; ++c)
            gload_lds16(bg + k0 + (size_t)c * 8 * K, bLds + c * 512);
        __syncthreads();

#pragma unroll
        for (int kk = 0; kk < 2; ++kk) {
            bf16x8 afr[4], bfr[4];
            const int cb = ((kk * 4 + fg) ^ sw) << 3;
#pragma unroll
            for (int mm = 0; mm < 4; ++mm)
                afr[mm] = *(const bf16x8*)(As + aRow + mm * 1024 + cb);
#pragma unroll
            for (int nn = 0; nn < 4; ++nn)
                bfr[nn] = *(const bf16x8*)(Bs + bRow + nn * 1024 + cb);
#pragma unroll
            for (int mm = 0; mm < 4; ++mm)
#pragma unroll
                for (int nn = 0; nn < 4; ++nn)
                    acc[mm][nn] = MFMA16(afr[mm], bfr[nn], acc[mm][nn]);
        }
    }

    // ---- epilogue
    const int lc = lane & 15;
    const int lr = (lane >> 4) * 4;

    if (MODE == 4 && n0 >= 1536) {
        // V tile: LDS-bounce transpose -> vtb[b][d][t] with us8 (16B) stores.
        // Each wave uses its private 8KB quarter of As (dead after K-loop).
        __syncthreads();   // all waves done reading As/Bs
        unsigned short* Vl = As + wv * 4096;   // [64 d][64 t] shorts, swizzled
#pragma unroll
        for (int mm = 0; mm < 4; ++mm) {
            const int s = mm * 4 + (lane >> 4);     // 8B t-slot 0..15
            const int sp = s >> 1, so = s & 1;      // 16B pair + half
#pragma unroll
            for (int nn = 0; nn < 4; ++nn) {
                const int d = nn * 16 + lc;
                const float bv = bias3[(n0 - 1536) + wc * 64 + d];
                us4 pk;
#pragma unroll
                for (int r = 0; r < 4; ++r) pk[r] = f2bf(acc[mm][nn][r] + bv);
                *(us4*)(Vl + d * 64 + ((sp ^ (d & 7)) << 3) + so * 4) = pk;
            }
        }
        asm volatile("s_waitcnt lgkmcnt(0)" ::: "memory");   // own-wave writes done
        const int bb = m0 >> 11;                 // batch = m0/2048
        const int tl0 = (m0 & 2047) + wr * 64;   // t-base of this wave
        const size_t rowbase = (size_t)(bb * D_ + (n0 - 1536) + wc * 64);
        unsigned short* vout = (unsigned short*)out3;
#pragma unroll
        for (int it = 0; it < 8; ++it) {
            const int d = (lane >> 3) + it * 8;
            const int c = lane & 7;              // 16B t-chunk
            const us8 v = *(const us8*)(Vl + d * 64 + ((c ^ (d & 7)) << 3));
            *(us8*)(vout + (rowbase + d) * (size_t)T_ + tl0 + c * 8) = v;
        }
        return;
    }

#pragma unroll
    for (int mm = 0; mm < 4; ++mm) {
        const int gm0 = m0 + wr * 64 + mm * 16 + lr;
#pragma unroll
        for (int nn = 0; nn < 4; ++nn) {
            const int gn = n0 + wc * 64 + nn * 16 + lc;
            if (MODE == 4) {
                // tile-uniform Q/K routing (tiles never straddle 768/1536)
                const bool isQ = (n0 < 768);
                unsigned short* o = isQ ? (unsigned short*)outp : (unsigned short*)out2;
                const int col = isQ ? gn : gn - 768;
                const float bv = isQ ? bias[col] : bias2[col];
#pragma unroll
                for (int r = 0; r < 4; ++r)
                    o[(size_t)(gm0 + r) * 768 + col] = f2bf(acc[mm][nn][r] + bv);
            } else if (MODE == 5) {
                unsigned short* o = (unsigned short*)outp + (size_t)ks * partStride;
#pragma unroll
                for (int r = 0; r < 4; ++r)
                    o[(size_t)(gm0 + r) * N + gn] = f2bf(acc[mm][nn][r]);
            } else {
                const float bv = bias[gn];
#pragma unroll
                for (int r = 0; r < 4; ++r) {
                    const int gm = gm0 + r;
                    float v = acc[mm][nn][r] + bv;
                    if (MODE == 0) {
                        ((unsigned short*)outp)[(size_t)gm * N + gn] = f2bf(v);
                    } else if (MODE == 2) {
                        ((unsigned short*)outp)[(size_t)gm * N + gn] = f2bf(gelu_fast(v));
                    }
                }
            }
        }
    }
}

// ---------------- banded flash attention ----------------
// block = 256 threads (4 waves), handles (b, h, 64-query tile)
// K/V window = [t0, t1), KW <= 192
__global__ __launch_bounds__(256) void attn_kernel(
    const unsigned short* __restrict__ Q,    // [B*T][768]
    const unsigned short* __restrict__ Kg,   // [B*T][768]
    const unsigned short* __restrict__ Vt,   // [B][768][T]
    unsigned short* __restrict__ ctx)        // [B*T][768]
{
    __shared__ __align__(16) unsigned short Qs[64][72];
    __shared__ __align__(16) unsigned short KP[192 * 72];   // Ks, later Ps[64][200]
    __shared__ __align__(16) unsigned short Vts[64][200];

    const int tid = threadIdx.x;
    const int lane = tid & 63;
    const int w = tid >> 6;
    const int bid = blockIdx.x;
    const int qt = bid & 31;
    const int h = (bid >> 5) % H_;
    const int b = bid / (32 * H_);
    const int qs = qt * 64;
    const int t0 = qs >= 64 ? qs - 64 : 0;
    const int t1 = (qs + 128 < T_) ? qs + 128 : T_;
    const int KW = t1 - t0;

    for (int s = tid; s < 512; s += 256) {
        const int r = s >> 3, c8 = (s & 7) << 3;
        *(uint4*)&Qs[r][c8] =
            *(const uint4*)&Q[((size_t)(b * T_ + qs + r)) * D_ + h * DH_ + c8];
    }
    unsigned short* Ks = KP;
    for (int s = tid; s < 1536; s += 256) {
        const int r = s >> 3, c8 = (s & 7) << 3;
        uint4 val = {0, 0, 0, 0};
        if (r < KW)
            val = *(const uint4*)&Kg[((size_t)(b * T_ + t0 + r)) * D_ + h * DH_ + c8];
        *(uint4*)&Ks[r * 72 + c8] = val;
    }
    for (int s = tid; s < 1536; s += 256) {
        const int r = s / 24, c8 = (s % 24) << 3;
        uint4 val = {0, 0, 0, 0};
        if (c8 < KW)
            val = *(const uint4*)&Vt[((size_t)((b * H_ + h) * DH_ + r)) * T_ + t0 + c8];
        *(uint4*)&Vts[r][c8] = val;
    }
    __syncthreads();

    f32x4 zero4 = {0.0f, 0.0f, 0.0f, 0.0f};
    f32x4 sa[12];
#pragma unroll
    for (int i = 0; i < 12; ++i) sa[i] = zero4;
#pragma unroll
    for (int ks = 0; ks < 2; ++ks) {
        const bf16x8 aq = *(const bf16x8*)&Qs[w * 16 + (lane & 15)][ks * 32 + (lane >> 4) * 8];
#pragma unroll
        for (int cf = 0; cf < 12; ++cf) {
            const bf16x8 bk = *(const bf16x8*)&Ks[(cf * 16 + (lane & 15)) * 72 + ks * 32 + (lane >> 4) * 8];
            sa[cf] = MFMA16(aq, bk, sa[cf]);
        }
    }
    __syncthreads();

    const int lq = w * 16 + (lane >> 4) * 4;
    float mx[4] = {-1e30f, -1e30f, -1e30f, -1e30f};
#pragma unroll
    for (int cf = 0; cf < 12; ++cf) {
        const int key = t0 + cf * 16 + (lane & 15);
#pragma unroll
        for (int r = 0; r < 4; ++r) {
            const int dd = (qs + lq + r) - key;
            const bool ok = (key < t1) && (dd <= 64) && (dd >= -64);
            const float sv = ok ? sa[cf][r] * 0.125f : -1e30f;
            sa[cf][r] = sv;
            mx[r] = fmaxf(mx[r], sv);
        }
    }
#pragma unroll
    for (int r = 0; r < 4; ++r)
#pragma unroll
        for (int o = 1; o < 16; o <<= 1)
            mx[r] = fmaxf(mx[r], __shfl_xor(mx[r], o));

    unsigned short* Ps = KP;
    float sm[4] = {0.0f, 0.0f, 0.0f, 0.0f};
#pragma unroll
    for (int cf = 0; cf < 12; ++cf) {
#pragma unroll
        for (int r = 0; r < 4; ++r) {
            const float p = __expf(sa[cf][r] - mx[r]);
            sm[r] += p;
            Ps[(lq + r) * 200 + cf * 16 + (lane & 15)] = f2bf(p);
        }
    }
#pragma unroll
    for (int r = 0; r < 4; ++r)
#pragma unroll
        for (int o = 1; o < 16; o <<= 1)
            sm[r] += __shfl_xor(sm[r], o);

    f32x4 oa[4];
#pragma unroll
    for (int i = 0; i < 4; ++i) oa[i] = zero4;
#pragma unroll
    for (int ks = 0; ks < 6; ++ks) {
        const bf16x8 ap = *(const bf16x8*)&Ps[(w * 16 + (lane & 15)) * 200 + ks * 32 + (lane >> 4) * 8];
#pragma unroll
        for (int nf = 0; nf < 4; ++nf) {
            const bf16x8 bv = *(const bf16x8*)&Vts[nf * 16 + (lane & 15)][ks * 32 + (lane >> 4) * 8];
            oa[nf] = MFMA16(ap, bv, oa[nf]);
        }
    }
#pragma unroll
    for (int nf = 0; nf < 4; ++nf) {
#pragma unroll
        for (int r = 0; r < 4; ++r) {
            const float o = oa[nf][r] / sm[r];
            ctx[((size_t)(b * T_ + qs + lq + r)) * D_ + h * DH_ + nf * 16 + (lane & 15)] = f2bf(o);
        }
    }
}

// ---------------- orchestration ----------------
extern "C" void kernel_launch(void* const* d_in, const int* in_sizes, int n_in,
                              void* d_out, int out_size, void* d_ws, size_t ws_size,
                              hipStream_t stream)
{
    const float* x   = (const float*)d_in[0];
    const float* Wq  = (const float*)d_in[1];
    const float* bq  = (const float*)d_in[2];
    const float* Wk  = (const float*)d_in[3];
    const float* bk  = (const float*)d_in[4];
    const float* Wv  = (const float*)d_in[5];
    const float* bv  = (const float*)d_in[6];
    const float* Wo  = (const float*)d_in[7];
    const float* bo  = (const float*)d_in[8];
    const float* W1  = (const float*)d_in[9];
    const float* b1  = (const float*)d_in[10];
    const float* W2  = (const float*)d_in[11];
    const float* b2  = (const float*)d_in[12];
    const float* g1  = (const float*)d_in[13];
    const float* be1 = (const float*)d_in[14];
    const float* g2  = (const float*)d_in[15];
    const float* be2 = (const float*)d_in[16];
    float* out = (float*)d_out;

    unsigned short* wqkv_t = (unsigned short*)d_ws;        // 3 x [768][768]
    unsigned short* wo_t = wqkv_t + 3 * 589824;
    unsigned short* w1_t = wo_t + 589824;                  // [3072][768]
    unsigned short* w2_t = w1_t + 2359296;                 // [768][3072]
    unsigned short* hbuf = w2_t + 2359296;                 // h1, ctx, FF2-partials
    unsigned short* qbuf = hbuf + 6291456;                 // q, h2, FF2-partial hi
    unsigned short* x2b  = qbuf + 6291456;                 // x2 bf16 (uses half of old fp32 slot)
    unsigned short* kbuf = x2b + 2 * 6291456;              // k, Wo-partials (offsets preserved)
    unsigned short* vtb  = kbuf + 6291456;                 // [4][768][2048], Wo-partial hi
    unsigned short* ffb  = kbuf;                           // [8192][3072]

    dim3 tb(32, 8);
    tcvt4_kernel<<<dim3(24, 24, 4), tb, 0, stream>>>(Wq, Wk, Wv, Wo, wqkv_t);
    tcvt_kernel<<<dim3(96, 24), tb, 0, stream>>>(W1, w1_t, 768, 3072);
    tcvt_kernel<<<dim3(24, 96), tb, 0, stream>>>(W2, w2_t, 3072, 768);

    ln_kernel<<<2048, 256, 0, stream>>>(x, g1, be1, hbuf);

    // fused QKV: N = 2304, routes Q->qbuf, K->kbuf, V->vtb(transposed)
    gemm4w<4><<<64 * 18, 256, 0, stream>>>(
        hbuf, wqkv_t, bq, bk, bv, qbuf, kbuf, vtb, 2304, 768, 768, 18, 64 * 18, 0);

    attn_kernel<<<1536, 256, 0, stream>>>(qbuf, kbuf, vtb, hbuf);   // ctx -> hbuf

    // Wo: split-K S=2 (K'=384), bf16 partials into dead kbuf/vtb region
    gemm4w<5><<<64 * 6 * 2, 256, 0, stream>>>(
        hbuf, wo_t, nullptr, nullptr, nullptr, kbuf, nullptr, nullptr,
        768, 768, 384, 6, 64 * 6, 6291456);

    // fused reduce + residual + LN2: x2 (bf16) and h2 (bf16 -> qbuf)
    reduce_ln_kernel<<<2048, 256, 0, stream>>>(
        kbuf, kbuf + 6291456, x, bo, g2, be2, x2b, qbuf);

    // FF1: gelu_fast -> ffb (overwrites dead Wo partials)
    gemm4w<2><<<64 * 24, 256, 0, stream>>>(
        qbuf, w1_t, b1, nullptr, nullptr, ffb, nullptr, nullptr,
        3072, 768, 768, 24, 64 * 24, 0);

    // FF2: split-K S=2 (K'=1536), bf16 partials into dead hbuf/qbuf region
    gemm4w<5><<<64 * 6 * 2, 256, 0, stream>>>(
        ffb, w2_t, nullptr, nullptr, nullptr, hbuf, nullptr, nullptr,
        768, 3072, 1536, 6, 64 * 6, 6291456);

    reduce_out_kernel<<<2048, 256, 0, stream>>>(
        hbuf, hbuf + 6291456, x2b, b2, out);
}

// Round 12
// 214.931 us; speedup vs baseline: 1.2254x; 1.0382x over previous
//
#include <hip/hip_runtime.h>
#include <hip/hip_bf16.h>

#define B_  4
#define T_  2048
#define D_  768
#define H_  12
#define DH_ 64
#define FF_ 3072

typedef __attribute__((ext_vector_type(8))) short bf16x8;
typedef __attribute__((ext_vector_type(4))) float f32x4;
typedef __attribute__((ext_vector_type(4))) unsigned short us4;
typedef __attribute__((ext_vector_type(8))) unsigned short us8;

#define MFMA16(a, b, c) __builtin_amdgcn_mfma_f32_16x16x32_bf16((a), (b), (c), 0, 0, 0)

__device__ __forceinline__ unsigned short f2bf(float f) {
    union { float f; unsigned u; } v; v.f = f;
    unsigned r = v.u + 0x7fffu + ((v.u >> 16) & 1u);
    return (unsigned short)(r >> 16);
}
__device__ __forceinline__ float bf2f(unsigned short s) {
    union { unsigned u; float f; } v; v.u = ((unsigned)s) << 16;
    return v.f;
}

// cheap GELU: tanh form, |err vs exact| <= ~2e-4 (invisible at bf16 + W2 smear)
__device__ __forceinline__ float gelu_fast(float v) {
    const float u2 = 2.0f * v * fmaf(0.0356774081f, v * v, 0.7978845608f);
    const float e = __expf(u2);                      // e^(2u)
    const float r = __builtin_amdgcn_rcpf(e + 1.0f); // 1/(e+1)
    const float th = fmaf(-2.0f, r, 1.0f);           // tanh(u)
    return 0.5f * v * (1.0f + th);
}

// async global->LDS, 16B per lane. LDS dest must be wave-uniform; HW adds lane*16.
__device__ __forceinline__ void gload_lds16(const unsigned short* gp, unsigned short* lp) {
    __builtin_amdgcn_global_load_lds(
        (const __attribute__((address_space(1))) unsigned int*)gp,
        (__attribute__((address_space(3))) unsigned int*)lp,
        16, 0, 0);
}

// ---------------- fused prep kernel: all weight transposes + LN1 in ONE launch ----
// segments (flat blockIdx.x):
//   [0, 2304)      : 4 x 768x768 tcvt (Wq,Wk,Wv,Wo -> wqkv_t contiguous)
//   [2304, 4608)   : W1 [768][3072] -> w1_t [3072][768]
//   [4608, 6912)   : W2 [3072][768] -> w2_t [768][3072]
//   [6912, 8960)   : LN1 (4 rows per block, wave per row)
__global__ __launch_bounds__(256) void prep_kernel(
    const float* __restrict__ Wq, const float* __restrict__ Wk,
    const float* __restrict__ Wv, const float* __restrict__ Wo,
    const float* __restrict__ W1, const float* __restrict__ W2,
    unsigned short* __restrict__ wqkv_t, unsigned short* __restrict__ w1_t,
    unsigned short* __restrict__ w2_t,
    const float* __restrict__ x, const float* __restrict__ g,
    const float* __restrict__ be, unsigned short* __restrict__ h1)
{
    const int bid = blockIdx.x;
    const int tid = threadIdx.x;

    if (bid >= 6912) {
        // ---- LN1 segment ----
        const int lane = tid & 63;
        const int row = (bid - 6912) * 4 + (tid >> 6);
        const float4* xr = (const float4*)(x + (size_t)row * D_);
        float4 v0 = xr[lane], v1 = xr[lane + 64], v2 = xr[lane + 128];
        float s  = v0.x + v0.y + v0.z + v0.w + v1.x + v1.y + v1.z + v1.w
                 + v2.x + v2.y + v2.z + v2.w;
        float s2 = v0.x*v0.x + v0.y*v0.y + v0.z*v0.z + v0.w*v0.w
                 + v1.x*v1.x + v1.y*v1.y + v1.z*v1.z + v1.w*v1.w
                 + v2.x*v2.x + v2.y*v2.y + v2.z*v2.z + v2.w*v2.w;
#pragma unroll
        for (int o = 1; o < 64; o <<= 1) {
            s  += __shfl_xor(s,  o);
            s2 += __shfl_xor(s2, o);
        }
        const float mu = s * (1.0f / D_);
        const float var = s2 * (1.0f / D_) - mu * mu;
        const float rstd = rsqrtf(var + 1e-5f);
        const float4* gv = (const float4*)g;
        const float4* bv = (const float4*)be;
        us4* orow = (us4*)(h1 + (size_t)row * D_);
#pragma unroll
        for (int k = 0; k < 3; ++k) {
            const float4 v = (k == 0) ? v0 : (k == 1) ? v1 : v2;
            const float4 gg = gv[lane + k * 64];
            const float4 bb = bv[lane + k * 64];
            us4 p;
            p[0] = f2bf((v.x - mu) * rstd * gg.x + bb.x);
            p[1] = f2bf((v.y - mu) * rstd * gg.y + bb.y);
            p[2] = f2bf((v.z - mu) * rstd * gg.z + bb.z);
            p[3] = f2bf((v.w - mu) * rstd * gg.w + bb.w);
            orow[lane + k * 64] = p;
        }
        return;
    }

    // ---- transpose segments: src[K][N] f32 -> dst[N][K] bf16, 32x32 tiles ----
    __shared__ float tile[32][33];
    const float* src;
    unsigned short* dst;
    int N, K, bx, by;
    if (bid < 2304) {
        const int z = bid / 576;
        const int t = bid - z * 576;
        src = (z == 0) ? Wq : (z == 1) ? Wk : (z == 2) ? Wv : Wo;
        dst = wqkv_t + (size_t)z * 589824;
        N = 768; K = 768;
        bx = (t % 24) * 32; by = (t / 24) * 32;
    } else if (bid < 4608) {
        const int t = bid - 2304;
        src = W1; dst = w1_t; N = 3072; K = 768;
        bx = (t % 96) * 32; by = (t / 96) * 32;
    } else {
        const int t = bid - 4608;
        src = W2; dst = w2_t; N = 768; K = 3072;
        bx = (t % 24) * 32; by = (t / 24) * 32;
    }
    const int tx = tid & 31, ty = tid >> 5;   // 32 x 8
#pragma unroll
    for (int i = 0; i < 32; i += 8)
        tile[ty + i][tx] = src[(size_t)(by + ty + i) * N + bx + tx];
    __syncthreads();
#pragma unroll
    for (int i = 0; i < 32; i += 8)
        dst[(size_t)(bx + ty + i) * K + by + tx] = f2bf(tile[tx][ty + i]);
}

// ---- fused split-K reduce + residual + LayerNorm (Wo path) ----
// x2 = p0 + p1 + bo + x (stored bf16); h2 = LN(x2)*g2+be2 (bf16).
__global__ __launch_bounds__(256) void reduce_ln_kernel(
    const unsigned short* __restrict__ p0, const unsigned short* __restrict__ p1,
    const float* __restrict__ x, const float* __restrict__ bo,
    const float* __restrict__ g, const float* __restrict__ be,
    unsigned short* __restrict__ x2, unsigned short* __restrict__ h2)
{
    const int lane = threadIdx.x & 63;
    const int row = blockIdx.x * 4 + (threadIdx.x >> 6);
    const size_t base = (size_t)row * D_;
    float v[12];
    float s = 0.0f, s2 = 0.0f;
#pragma unroll
    for (int k = 0; k < 3; ++k) {
        const int c = k * 256 + lane * 4;
        const us4 a = *(const us4*)(p0 + base + c);
        const us4 b = *(const us4*)(p1 + base + c);
        const float4 xr = *(const float4*)(x + base + c);
        const float4 bb = *(const float4*)(bo + c);
        const float w0 = bf2f(a[0]) + bf2f(b[0]) + bb.x + xr.x;
        const float w1 = bf2f(a[1]) + bf2f(b[1]) + bb.y + xr.y;
        const float w2 = bf2f(a[2]) + bf2f(b[2]) + bb.z + xr.z;
        const float w3 = bf2f(a[3]) + bf2f(b[3]) + bb.w + xr.w;
        v[k * 4 + 0] = w0; v[k * 4 + 1] = w1; v[k * 4 + 2] = w2; v[k * 4 + 3] = w3;
        s += w0 + w1 + w2 + w3;
        s2 += w0 * w0 + w1 * w1 + w2 * w2 + w3 * w3;
    }
#pragma unroll
    for (int o = 1; o < 64; o <<= 1) {
        s  += __shfl_xor(s,  o);
        s2 += __shfl_xor(s2, o);
    }
    const float mu = s * (1.0f / D_);
    const float var = s2 * (1.0f / D_) - mu * mu;
    const float rstd = rsqrtf(var + 1e-5f);
#pragma unroll
    for (int k = 0; k < 3; ++k) {
        const int c = k * 256 + lane * 4;
        const float4 gg = *(const float4*)(g + c);
        const float4 bb = *(const float4*)(be + c);
        us4 xo, ho;
        xo[0] = f2bf(v[k*4+0]); xo[1] = f2bf(v[k*4+1]);
        xo[2] = f2bf(v[k*4+2]); xo[3] = f2bf(v[k*4+3]);
        ho[0] = f2bf((v[k*4+0] - mu) * rstd * gg.x + bb.x);
        ho[1] = f2bf((v[k*4+1] - mu) * rstd * gg.y + bb.y);
        ho[2] = f2bf((v[k*4+2] - mu) * rstd * gg.z + bb.z);
        ho[3] = f2bf((v[k*4+3] - mu) * rstd * gg.w + bb.w);
        *(us4*)(x2 + base + c) = xo;
        *(us4*)(h2 + base + c) = ho;
    }
}

// ---- split-K reduce + bias + residual (FF2 path, fp32 out; x2 bf16) ----
__global__ __launch_bounds__(256) void reduce_out_kernel(
    const unsigned short* __restrict__ p0, const unsigned short* __restrict__ p1,
    const unsigned short* __restrict__ x2, const float* __restrict__ b2,
    float* __restrict__ out)
{
    const int n4 = B_ * T_ * D_ / 4;
    for (int i = blockIdx.x * 256 + threadIdx.x; i < n4; i += gridDim.x * 256) {
        const us4 a = ((const us4*)p0)[i];
        const us4 b = ((const us4*)p1)[i];
        const us4 xr = ((const us4*)x2)[i];
        const int col = (i * 4) % D_;
        const float4 bb = *(const float4*)(b2 + col);
        float4 o;
        o.x = bf2f(a[0]) + bf2f(b[0]) + bb.x + bf2f(xr[0]);
        o.y = bf2f(a[1]) + bf2f(b[1]) + bb.y + bf2f(xr[1]);
        o.z = bf2f(a[2]) + bf2f(b[2]) + bb.z + bf2f(xr[2]);
        o.w = bf2f(a[3]) + bf2f(b[3]) + bb.w + bf2f(xr[3]);
        ((float4*)out)[i] = o;
    }
}

// ---------------- 4-wave m97-structure GEMM: C = A[M][K] * Bt[N][K]^T ----------------
// BM=BN=128, BK=64; 256 threads (4 waves 2x2), wave-tile 64x64 (acc 4x4).
// LDS 32KB, ~3 blocks/CU co-residency hides latency. LDS rows = 64 shorts =
// 8 x 16B blocks; block b of row r at b^(r&7) via pre-swizzled global SOURCE
// (gload dest linear); ds_read same XOR -> measured 0 bank conflicts.
// 1D grid over (ks, mTile, nTile), N-fastest; bijective XCD swizzle.
// MODE 0: bf16 out; MODE 2: gelu_fast->bf16; MODE 4: fused QKV routing
// (tile-uniform: n0<768 Q, <1536 K, else V via LDS-bounce transposed us8
//  stores); MODE 5: bf16 partial (split-K).
template<int MODE>
__global__ __launch_bounds__(256, 3) void gemm4w(
    const unsigned short* __restrict__ A,
    const unsigned short* __restrict__ Bt,
    const float* __restrict__ bias,
    const float* __restrict__ bias2,
    const float* __restrict__ bias3,
    void* __restrict__ outp,
    void* __restrict__ out2,
    void* __restrict__ out3,
    int N, int K, int kLen, int nTilesN, int nTilesMN, long partStride)
{
    __shared__ __align__(16) unsigned short As[128 * 64];
    __shared__ __align__(16) unsigned short Bs[128 * 64];

    // bijective XCD swizzle (m204)
    const int nwg = gridDim.x;
    const int q = nwg >> 3, rr = nwg & 7;
    const int xcd = blockIdx.x & 7, loc = blockIdx.x >> 3;
    const int swz = (xcd < rr ? xcd * (q + 1) : rr * (q + 1) + (xcd - rr) * q) + loc;
    const int ks  = swz / nTilesMN;
    const int rem = swz - ks * nTilesMN;
    const int m0 = (rem / nTilesN) * 128;
    const int n0 = (rem % nTilesN) * 128;
    const int kOff = ks * kLen;

    const int tid = threadIdx.x;
    const int wv = tid >> 6;
    const int lane = tid & 63;
    const int wr = wv >> 1;          // 0..1 (M)
    const int wc = wv & 1;           // 0..1 (N)

    f32x4 zero4 = {0.0f, 0.0f, 0.0f, 0.0f};
    f32x4 acc[4][4];
#pragma unroll
    for (int i = 0; i < 4; ++i)
#pragma unroll
        for (int j = 0; j < 4; ++j) acc[i][j] = zero4;

    // staging: each wave stages 32 rows of A and 32 rows of B (4 chunks of
    // 8 rows x 64 shorts). lane -> (lrow=lane>>3, blk=lane&7);
    // source col-block = blk ^ lrow (chunk bases are multiples of 8 rows).
    const int lrow = lane >> 3;
    const int scb = (lane & 7) ^ lrow;
    const unsigned short* ag = A  + (size_t)(m0 + wv * 32 + lrow) * K + kOff + scb * 8;
    const unsigned short* bg = Bt + (size_t)(n0 + wv * 32 + lrow) * K + kOff + scb * 8;
    unsigned short* aLds = As + wv * 32 * 64;
    unsigned short* bLds = Bs + wv * 32 * 64;

    // fragment-read setup
    const int fr = lane & 15;
    const int fg = lane >> 4;        // 0..3
    const int sw = fr & 7;
    const int aRow = (wr * 64 + fr) * 64;   // + mm*16*64
    const int bRow = (wc * 64 + fr) * 64;   // + nn*16*64

    const int nk = kLen >> 6;
    for (int kt = 0; kt < nk; ++kt) {
        const int k0 = kt << 6;
        __syncthreads();
#pragma unroll
        for (int c = 0; c < 4; ++c)
            gload_lds16(ag + k0 + (size_t)c * 8 * K, aLds + c * 512);
#pragma unroll
        for (int c = 0; c < 4; ++c)
            gload_lds16(bg + k0 + (size_t)c * 8 * K, bLds + c * 512);
        __syncthreads();

#pragma unroll
        for (int kk = 0; kk < 2; ++kk) {
            bf16x8 afr[4], bfr[4];
            const int cb = ((kk * 4 + fg) ^ sw) << 3;
#pragma unroll
            for (int mm = 0; mm < 4; ++mm)
                afr[mm] = *(const bf16x8*)(As + aRow + mm * 1024 + cb);
#pragma unroll
            for (int nn = 0; nn < 4; ++nn)
                bfr[nn] = *(const bf16x8*)(Bs + bRow + nn * 1024 + cb);
#pragma unroll
            for (int mm = 0; mm < 4; ++mm)
#pragma unroll
                for (int nn = 0; nn < 4; ++nn)
                    acc[mm][nn] = MFMA16(afr[mm], bfr[nn], acc[mm][nn]);
        }
    }

    // ---- epilogue
    const int lc = lane & 15;
    const int lr = (lane >> 4) * 4;

    if (MODE == 4 && n0 >= 1536) {
        // V tile: LDS-bounce transpose -> vtb[b][d][t] with us8 (16B) stores.
        __syncthreads();   // all waves done reading As/Bs
        unsigned short* Vl = As + wv * 4096;   // [64 d][64 t] shorts, swizzled
#pragma unroll
        for (int mm = 0; mm < 4; ++mm) {
            const int s = mm * 4 + (lane >> 4);     // 8B t-slot 0..15
            const int sp = s >> 1, so = s & 1;      // 16B pair + half
#pragma unroll
            for (int nn = 0; nn < 4; ++nn) {
                const int d = nn * 16 + lc;
                const float bv = bias3[(n0 - 1536) + wc * 64 + d];
                us4 pk;
#pragma unroll
                for (int r = 0; r < 4; ++r) pk[r] = f2bf(acc[mm][nn][r] + bv);
                *(us4*)(Vl + d * 64 + ((sp ^ (d & 7)) << 3) + so * 4) = pk;
            }
        }
        asm volatile("s_waitcnt lgkmcnt(0)" ::: "memory");
        const int bb = m0 >> 11;                 // batch = m0/2048
        const int tl0 = (m0 & 2047) + wr * 64;   // t-base of this wave
        const size_t rowbase = (size_t)(bb * D_ + (n0 - 1536) + wc * 64);
        unsigned short* vout = (unsigned short*)out3;
#pragma unroll
        for (int it = 0; it < 8; ++it) {
            const int d = (lane >> 3) + it * 8;
            const int c = lane & 7;              // 16B t-chunk
            const us8 v = *(const us8*)(Vl + d * 64 + ((c ^ (d & 7)) << 3));
            *(us8*)(vout + (rowbase + d) * (size_t)T_ + tl0 + c * 8) = v;
        }
        return;
    }

#pragma unroll
    for (int mm = 0; mm < 4; ++mm) {
        const int gm0 = m0 + wr * 64 + mm * 16 + lr;
#pragma unroll
        for (int nn = 0; nn < 4; ++nn) {
            const int gn = n0 + wc * 64 + nn * 16 + lc;
            if (MODE == 4) {
                const bool isQ = (n0 < 768);
                unsigned short* o = isQ ? (unsigned short*)outp : (unsigned short*)out2;
                const int col = isQ ? gn : gn - 768;
                const float bv = isQ ? bias[col] : bias2[col];
#pragma unroll
                for (int r = 0; r < 4; ++r)
                    o[(size_t)(gm0 + r) * 768 + col] = f2bf(acc[mm][nn][r] + bv);
            } else if (MODE == 5) {
                unsigned short* o = (unsigned short*)outp + (size_t)ks * partStride;
#pragma unroll
                for (int r = 0; r < 4; ++r)
                    o[(size_t)(gm0 + r) * N + gn] = f2bf(acc[mm][nn][r]);
            } else {
                const float bv = bias[gn];
#pragma unroll
                for (int r = 0; r < 4; ++r) {
                    const int gm = gm0 + r;
                    float v = acc[mm][nn][r] + bv;
                    if (MODE == 0) {
                        ((unsigned short*)outp)[(size_t)gm * N + gn] = f2bf(v);
                    } else if (MODE == 2) {
                        ((unsigned short*)outp)[(size_t)gm * N + gn] = f2bf(gelu_fast(v));
                    }
                }
            }
        }
    }
}

// ---------------- banded flash attention ----------------
// block = 256 threads (4 waves), handles (b, h, 64-query tile).
// T1 XCD swizzle: 1536 blocks % 8 == 0 -> consecutive logical tiles (adjacent
// qt, sharing 128/192 K/V rows) land on the SAME XCD L2.
__global__ __launch_bounds__(256) void attn_kernel(
    const unsigned short* __restrict__ Q,    // [B*T][768]
    const unsigned short* __restrict__ Kg,   // [B*T][768]
    const unsigned short* __restrict__ Vt,   // [B][768][T]
    unsigned short* __restrict__ ctx)        // [B*T][768]
{
    __shared__ __align__(16) unsigned short Qs[64][72];
    __shared__ __align__(16) unsigned short KP[192 * 72];   // Ks, later Ps[64][200]
    __shared__ __align__(16) unsigned short Vts[64][200];

    const int tid = threadIdx.x;
    const int lane = tid & 63;
    const int w = tid >> 6;
    // bijective XCD swizzle (nwg = 1536 = 8 * 192)
    const int bid = (blockIdx.x & 7) * 192 + (blockIdx.x >> 3);
    const int qt = bid & 31;
    const int h = (bid >> 5) % H_;
    const int b = bid / (32 * H_);
    const int qs = qt * 64;
    const int t0 = qs >= 64 ? qs - 64 : 0;
    const int t1 = (qs + 128 < T_) ? qs + 128 : T_;
    const int KW = t1 - t0;

    for (int s = tid; s < 512; s += 256) {
        const int r = s >> 3, c8 = (s & 7) << 3;
        *(uint4*)&Qs[r][c8] =
            *(const uint4*)&Q[((size_t)(b * T_ + qs + r)) * D_ + h * DH_ + c8];
    }
    unsigned short* Ks = KP;
    for (int s = tid; s < 1536; s += 256) {
        const int r = s >> 3, c8 = (s & 7) << 3;
        uint4 val = {0, 0, 0, 0};
        if (r < KW)
            val = *(const uint4*)&Kg[((size_t)(b * T_ + t0 + r)) * D_ + h * DH_ + c8];
        *(uint4*)&Ks[r * 72 + c8] = val;
    }
    for (int s = tid; s < 1536; s += 256) {
        const int r = s / 24, c8 = (s % 24) << 3;
        uint4 val = {0, 0, 0, 0};
        if (c8 < KW)
            val = *(const uint4*)&Vt[((size_t)((b * H_ + h) * DH_ + r)) * T_ + t0 + c8];
        *(uint4*)&Vts[r][c8] = val;
    }
    __syncthreads();

    f32x4 zero4 = {0.0f, 0.0f, 0.0f, 0.0f};
    f32x4 sa[12];
#pragma unroll
    for (int i = 0; i < 12; ++i) sa[i] = zero4;
#pragma unroll
    for (int ks = 0; ks < 2; ++ks) {
        const bf16x8 aq = *(const bf16x8*)&Qs[w * 16 + (lane & 15)][ks * 32 + (lane >> 4) * 8];
#pragma unroll
        for (int cf = 0; cf < 12; ++cf) {
            const bf16x8 bk = *(const bf16x8*)&Ks[(cf * 16 + (lane & 15)) * 72 + ks * 32 + (lane >> 4) * 8];
            sa[cf] = MFMA16(aq, bk, sa[cf]);
        }
    }
    __syncthreads();

    const int lq = w * 16 + (lane >> 4) * 4;
    float mx[4] = {-1e30f, -1e30f, -1e30f, -1e30f};
#pragma unroll
    for (int cf = 0; cf < 12; ++cf) {
        const int key = t0 + cf * 16 + (lane & 15);
#pragma unroll
        for (int r = 0; r < 4; ++r) {
            const int dd = (qs + lq + r) - key;
            const bool ok = (key < t1) && (dd <= 64) && (dd >= -64);
            const float sv = ok ? sa[cf][r] * 0.125f : -1e30f;
            sa[cf][r] = sv;
            mx[r] = fmaxf(mx[r], sv);
        }
    }
#pragma unroll
    for (int r = 0; r < 4; ++r)
#pragma unroll
        for (int o = 1; o < 16; o <<= 1)
            mx[r] = fmaxf(mx[r], __shfl_xor(mx[r], o));

    unsigned short* Ps = KP;
    float sm[4] = {0.0f, 0.0f, 0.0f, 0.0f};
#pragma unroll
    for (int cf = 0; cf < 12; ++cf) {
#pragma unroll
        for (int r = 0; r < 4; ++r) {
            const float p = __expf(sa[cf][r] - mx[r]);
            sm[r] += p;
            Ps[(lq + r) * 200 + cf * 16 + (lane & 15)] = f2bf(p);
        }
    }
#pragma unroll
    for (int r = 0; r < 4; ++r)
#pragma unroll
        for (int o = 1; o < 16; o <<= 1)
            sm[r] += __shfl_xor(sm[r], o);

    f32x4 oa[4];
#pragma unroll
    for (int i = 0; i < 4; ++i) oa[i] = zero4;
#pragma unroll
    for (int ks = 0; ks < 6; ++ks) {
        const bf16x8 ap = *(const bf16x8*)&Ps[(w * 16 + (lane & 15)) * 200 + ks * 32 + (lane >> 4) * 8];
#pragma unroll
        for (int nf = 0; nf < 4; ++nf) {
            const bf16x8 bv = *(const bf16x8*)&Vts[nf * 16 + (lane & 15)][ks * 32 + (lane >> 4) * 8];
            oa[nf] = MFMA16(ap, bv, oa[nf]);
        }
    }
#pragma unroll
    for (int nf = 0; nf < 4; ++nf) {
#pragma unroll
        for (int r = 0; r < 4; ++r) {
            const float o = oa[nf][r] / sm[r];
            ctx[((size_t)(b * T_ + qs + lq + r)) * D_ + h * DH_ + nf * 16 + (lane & 15)] = f2bf(o);
        }
    }
}

// ---------------- orchestration ----------------
extern "C" void kernel_launch(void* const* d_in, const int* in_sizes, int n_in,
                              void* d_out, int out_size, void* d_ws, size_t ws_size,
                              hipStream_t stream)
{
    const float* x   = (const float*)d_in[0];
    const float* Wq  = (const float*)d_in[1];
    const float* bq  = (const float*)d_in[2];
    const float* Wk  = (const float*)d_in[3];
    const float* bk  = (const float*)d_in[4];
    const float* Wv  = (const float*)d_in[5];
    const float* bv  = (const float*)d_in[6];
    const float* Wo  = (const float*)d_in[7];
    const float* bo  = (const float*)d_in[8];
    const float* W1  = (const float*)d_in[9];
    const float* b1  = (const float*)d_in[10];
    const float* W2  = (const float*)d_in[11];
    const float* b2  = (const float*)d_in[12];
    const float* g1  = (const float*)d_in[13];
    const float* be1 = (const float*)d_in[14];
    const float* g2  = (const float*)d_in[15];
    const float* be2 = (const float*)d_in[16];
    float* out = (float*)d_out;

    unsigned short* wqkv_t = (unsigned short*)d_ws;        // 3 x [768][768] (+wo)
    unsigned short* wo_t = wqkv_t + 3 * 589824;
    unsigned short* w1_t = wo_t + 589824;                  // [3072][768]
    unsigned short* w2_t = w1_t + 2359296;                 // [768][3072]
    unsigned short* hbuf = w2_t + 2359296;                 // h1, ctx, FF2-partials
    unsigned short* qbuf = hbuf + 6291456;                 // q, h2, FF2-partial hi
    unsigned short* x2b  = qbuf + 6291456;                 // x2 bf16
    unsigned short* kbuf = x2b + 2 * 6291456;              // k, Wo-partials
    unsigned short* vtb  = kbuf + 6291456;                 // [4][768][2048], Wo-partial hi
    unsigned short* ffb  = kbuf;                           // [8192][3072]

    // fused prep: all 6 weight transposes + LN1 in one launch
    prep_kernel<<<8960, 256, 0, stream>>>(
        Wq, Wk, Wv, Wo, W1, W2, wqkv_t, w1_t, w2_t, x, g1, be1, hbuf);

    // fused QKV: N = 2304, routes Q->qbuf, K->kbuf, V->vtb(transposed)
    gemm4w<4><<<64 * 18, 256, 0, stream>>>(
        hbuf, wqkv_t, bq, bk, bv, qbuf, kbuf, vtb, 2304, 768, 768, 18, 64 * 18, 0);

    attn_kernel<<<1536, 256, 0, stream>>>(qbuf, kbuf, vtb, hbuf);   // ctx -> hbuf

    // Wo: split-K S=2 (K'=384), bf16 partials into dead kbuf/vtb region
    gemm4w<5><<<64 * 6 * 2, 256, 0, stream>>>(
        hbuf, wo_t, nullptr, nullptr, nullptr, kbuf, nullptr, nullptr,
        768, 768, 384, 6, 64 * 6, 6291456);

    // fused reduce + residual + LN2: x2 (bf16) and h2 (bf16 -> qbuf)
    reduce_ln_kernel<<<2048, 256, 0, stream>>>(
        kbuf, kbuf + 6291456, x, bo, g2, be2, x2b, qbuf);

    // FF1: gelu_fast -> ffb (overwrites dead Wo partials)
    gemm4w<2><<<64 * 24, 256, 0, stream>>>(
        qbuf, w1_t, b1, nullptr, nullptr, ffb, nullptr, nullptr,
        3072, 768, 768, 24, 64 * 24, 0);

    // FF2: split-K S=2 (K'=1536), bf16 partials into dead hbuf/qbuf region
    gemm4w<5><<<64 * 6 * 2, 256, 0, stream>>>(
        ffb, w2_t, nullptr, nullptr, nullptr, hbuf, nullptr, nullptr,
        768, 3072, 1536, 6, 64 * 6, 6291456);

    reduce_out_kernel<<<2048, 256, 0, stream>>>(
        hbuf, hbuf + 6291456, x2b, b2, out);
}

// Round 13
// 213.728 us; speedup vs baseline: 1.2323x; 1.0056x over previous
//
#include <hip/hip_runtime.h>
#include <hip/hip_bf16.h>

#define B_  4
#define T_  2048
#define D_  768
#define H_  12
#define DH_ 64
#define FF_ 3072

typedef __attribute__((ext_vector_type(8))) short bf16x8;
typedef __attribute__((ext_vector_type(4))) float f32x4;
typedef __attribute__((ext_vector_type(4))) unsigned short us4;
typedef __attribute__((ext_vector_type(8))) unsigned short us8;

#define MFMA16(a, b, c) __builtin_amdgcn_mfma_f32_16x16x32_bf16((a), (b), (c), 0, 0, 0)

// use the HIP builtin conversion: compiler selects v_cvt_pk_bf16_f32 / optimal
// sequence (m240: compiler-generated beats hand-rolled bit-twiddle).
__device__ __forceinline__ unsigned short f2bf(float f) {
    __hip_bfloat16 h = __float2bfloat16(f);
    unsigned short u;
    __builtin_memcpy(&u, &h, 2);
    return u;
}
__device__ __forceinline__ float bf2f(unsigned short s) {
    union { unsigned u; float f; } v; v.u = ((unsigned)s) << 16;
    return v.f;
}

// cheap GELU: tanh form, |err vs exact| <= ~2e-4 (invisible at bf16 + W2 smear)
__device__ __forceinline__ float gelu_fast(float v) {
    const float u2 = 2.0f * v * fmaf(0.0356774081f, v * v, 0.7978845608f);
    const float e = __expf(u2);                      // e^(2u)
    const float r = __builtin_amdgcn_rcpf(e + 1.0f); // 1/(e+1)
    const float th = fmaf(-2.0f, r, 1.0f);           // tanh(u)
    return 0.5f * v * (1.0f + th);
}

// async global->LDS, 16B per lane. LDS dest must be wave-uniform; HW adds lane*16.
__device__ __forceinline__ void gload_lds16(const unsigned short* gp, unsigned short* lp) {
    __builtin_amdgcn_global_load_lds(
        (const __attribute__((address_space(1))) unsigned int*)gp,
        (__attribute__((address_space(3))) unsigned int*)lp,
        16, 0, 0);
}

// ---------------- fused prep kernel: all weight transposes + LN1 in ONE launch ----
// segments (flat blockIdx.x):
//   [0, 2304)      : 4 x 768x768 tcvt (Wq,Wk,Wv,Wo -> wqkv_t contiguous)
//   [2304, 4608)   : W1 [768][3072] -> w1_t [3072][768]
//   [4608, 6912)   : W2 [3072][768] -> w2_t [768][3072]
//   [6912, 8960)   : LN1 (4 rows per block, wave per row)
__global__ __launch_bounds__(256) void prep_kernel(
    const float* __restrict__ Wq, const float* __restrict__ Wk,
    const float* __restrict__ Wv, const float* __restrict__ Wo,
    const float* __restrict__ W1, const float* __restrict__ W2,
    unsigned short* __restrict__ wqkv_t, unsigned short* __restrict__ w1_t,
    unsigned short* __restrict__ w2_t,
    const float* __restrict__ x, const float* __restrict__ g,
    const float* __restrict__ be, unsigned short* __restrict__ h1)
{
    const int bid = blockIdx.x;
    const int tid = threadIdx.x;

    if (bid >= 6912) {
        // ---- LN1 segment ----
        const int lane = tid & 63;
        const int row = (bid - 6912) * 4 + (tid >> 6);
        const float4* xr = (const float4*)(x + (size_t)row * D_);
        float4 v0 = xr[lane], v1 = xr[lane + 64], v2 = xr[lane + 128];
        float s  = v0.x + v0.y + v0.z + v0.w + v1.x + v1.y + v1.z + v1.w
                 + v2.x + v2.y + v2.z + v2.w;
        float s2 = v0.x*v0.x + v0.y*v0.y + v0.z*v0.z + v0.w*v0.w
                 + v1.x*v1.x + v1.y*v1.y + v1.z*v1.z + v1.w*v1.w
                 + v2.x*v2.x + v2.y*v2.y + v2.z*v2.z + v2.w*v2.w;
#pragma unroll
        for (int o = 1; o < 64; o <<= 1) {
            s  += __shfl_xor(s,  o);
            s2 += __shfl_xor(s2, o);
        }
        const float mu = s * (1.0f / D_);
        const float var = s2 * (1.0f / D_) - mu * mu;
        const float rstd = rsqrtf(var + 1e-5f);
        const float4* gv = (const float4*)g;
        const float4* bv = (const float4*)be;
        us4* orow = (us4*)(h1 + (size_t)row * D_);
#pragma unroll
        for (int k = 0; k < 3; ++k) {
            const float4 v = (k == 0) ? v0 : (k == 1) ? v1 : v2;
            const float4 gg = gv[lane + k * 64];
            const float4 bb = bv[lane + k * 64];
            us4 p;
            p[0] = f2bf((v.x - mu) * rstd * gg.x + bb.x);
            p[1] = f2bf((v.y - mu) * rstd * gg.y + bb.y);
            p[2] = f2bf((v.z - mu) * rstd * gg.z + bb.z);
            p[3] = f2bf((v.w - mu) * rstd * gg.w + bb.w);
            orow[lane + k * 64] = p;
        }
        return;
    }

    // ---- transpose segments: src[K][N] f32 -> dst[N][K] bf16, 32x32 tiles ----
    __shared__ float tile[32][33];
    const float* src;
    unsigned short* dst;
    int N, K, bx, by;
    if (bid < 2304) {
        const int z = bid / 576;
        const int t = bid - z * 576;
        src = (z == 0) ? Wq : (z == 1) ? Wk : (z == 2) ? Wv : Wo;
        dst = wqkv_t + (size_t)z * 589824;
        N = 768; K = 768;
        bx = (t % 24) * 32; by = (t / 24) * 32;
    } else if (bid < 4608) {
        const int t = bid - 2304;
        src = W1; dst = w1_t; N = 3072; K = 768;
        bx = (t % 96) * 32; by = (t / 96) * 32;
    } else {
        const int t = bid - 4608;
        src = W2; dst = w2_t; N = 768; K = 3072;
        bx = (t % 24) * 32; by = (t / 24) * 32;
    }
    const int tx = tid & 31, ty = tid >> 5;   // 32 x 8
#pragma unroll
    for (int i = 0; i < 32; i += 8)
        tile[ty + i][tx] = src[(size_t)(by + ty + i) * N + bx + tx];
    __syncthreads();
#pragma unroll
    for (int i = 0; i < 32; i += 8)
        dst[(size_t)(bx + ty + i) * K + by + tx] = f2bf(tile[tx][ty + i]);
}

// ---- fused split-K reduce + residual + LayerNorm (Wo path) ----
// x2 = p0 + p1 + bo + x (stored bf16); h2 = LN(x2)*g2+be2 (bf16).
__global__ __launch_bounds__(256) void reduce_ln_kernel(
    const unsigned short* __restrict__ p0, const unsigned short* __restrict__ p1,
    const float* __restrict__ x, const float* __restrict__ bo,
    const float* __restrict__ g, const float* __restrict__ be,
    unsigned short* __restrict__ x2, unsigned short* __restrict__ h2)
{
    const int lane = threadIdx.x & 63;
    const int row = blockIdx.x * 4 + (threadIdx.x >> 6);
    const size_t base = (size_t)row * D_;
    float v[12];
    float s = 0.0f, s2 = 0.0f;
#pragma unroll
    for (int k = 0; k < 3; ++k) {
        const int c = k * 256 + lane * 4;
        const us4 a = *(const us4*)(p0 + base + c);
        const us4 b = *(const us4*)(p1 + base + c);
        const float4 xr = *(const float4*)(x + base + c);
        const float4 bb = *(const float4*)(bo + c);
        const float w0 = bf2f(a[0]) + bf2f(b[0]) + bb.x + xr.x;
        const float w1 = bf2f(a[1]) + bf2f(b[1]) + bb.y + xr.y;
        const float w2 = bf2f(a[2]) + bf2f(b[2]) + bb.z + xr.z;
        const float w3 = bf2f(a[3]) + bf2f(b[3]) + bb.w + xr.w;
        v[k * 4 + 0] = w0; v[k * 4 + 1] = w1; v[k * 4 + 2] = w2; v[k * 4 + 3] = w3;
        s += w0 + w1 + w2 + w3;
        s2 += w0 * w0 + w1 * w1 + w2 * w2 + w3 * w3;
    }
#pragma unroll
    for (int o = 1; o < 64; o <<= 1) {
        s  += __shfl_xor(s,  o);
        s2 += __shfl_xor(s2, o);
    }
    const float mu = s * (1.0f / D_);
    const float var = s2 * (1.0f / D_) - mu * mu;
    const float rstd = rsqrtf(var + 1e-5f);
#pragma unroll
    for (int k = 0; k < 3; ++k) {
        const int c = k * 256 + lane * 4;
        const float4 gg = *(const float4*)(g + c);
        const float4 bb = *(const float4*)(be + c);
        us4 xo, ho;
        xo[0] = f2bf(v[k*4+0]); xo[1] = f2bf(v[k*4+1]);
        xo[2] = f2bf(v[k*4+2]); xo[3] = f2bf(v[k*4+3]);
        ho[0] = f2bf((v[k*4+0] - mu) * rstd * gg.x + bb.x);
        ho[1] = f2bf((v[k*4+1] - mu) * rstd * gg.y + bb.y);
        ho[2] = f2bf((v[k*4+2] - mu) * rstd * gg.z + bb.z);
        ho[3] = f2bf((v[k*4+3] - mu) * rstd * gg.w + bb.w);
        *(us4*)(x2 + base + c) = xo;
        *(us4*)(h2 + base + c) = ho;
    }
}

// ---- split-K reduce + bias + residual (FF2 path, fp32 out; x2 bf16) ----
__global__ __launch_bounds__(256) void reduce_out_kernel(
    const unsigned short* __restrict__ p0, const unsigned short* __restrict__ p1,
    const unsigned short* __restrict__ x2, const float* __restrict__ b2,
    float* __restrict__ out)
{
    const int n4 = B_ * T_ * D_ / 4;
    for (int i = blockIdx.x * 256 + threadIdx.x; i < n4; i += gridDim.x * 256) {
        const us4 a = ((const us4*)p0)[i];
        const us4 b = ((const us4*)p1)[i];
        const us4 xr = ((const us4*)x2)[i];
        const int col = (i * 4) % D_;
        const float4 bb = *(const float4*)(b2 + col);
        float4 o;
        o.x = bf2f(a[0]) + bf2f(b[0]) + bb.x + bf2f(xr[0]);
        o.y = bf2f(a[1]) + bf2f(b[1]) + bb.y + bf2f(xr[1]);
        o.z = bf2f(a[2]) + bf2f(b[2]) + bb.z + bf2f(xr[2]);
        o.w = bf2f(a[3]) + bf2f(b[3]) + bb.w + bf2f(xr[3]);
        ((float4*)out)[i] = o;
    }
}

// ---------------- 4-wave m97-structure GEMM: C = A[M][K] * Bt[N][K]^T ----------------
// BM=BN=128, BK=64; 256 threads (4 waves 2x2), wave-tile 64x64 (acc 4x4).
// LDS 32KB; co-residency hides latency (launch_bounds hint 4 blocks/CU; LDS
// allows 5). LDS rows = 64 shorts = 8 x 16B blocks; block b of row r at
// b^(r&7) via pre-swizzled global SOURCE (gload dest linear); ds_read same
// XOR -> measured 0 bank conflicts.
// 1D grid over (ks, mTile, nTile), N-fastest; bijective XCD swizzle.
// MODE 0: bf16 out; MODE 2: gelu_fast->bf16; MODE 4: fused QKV routing
// (tile-uniform: n0<768 Q, <1536 K, else V via LDS-bounce transposed us8
//  stores); MODE 5: bf16 partial (split-K).
template<int MODE>
__global__ __launch_bounds__(256, 4) void gemm4w(
    const unsigned short* __restrict__ A,
    const unsigned short* __restrict__ Bt,
    const float* __restrict__ bias,
    const float* __restrict__ bias2,
    const float* __restrict__ bias3,
    void* __restrict__ outp,
    void* __restrict__ out2,
    void* __restrict__ out3,
    int N, int K, int kLen, int nTilesN, int nTilesMN, long partStride)
{
    __shared__ __align__(16) unsigned short As[128 * 64];
    __shared__ __align__(16) unsigned short Bs[128 * 64];

    // bijective XCD swizzle (m204)
    const int nwg = gridDim.x;
    const int q = nwg >> 3, rr = nwg & 7;
    const int xcd = blockIdx.x & 7, loc = blockIdx.x >> 3;
    const int swz = (xcd < rr ? xcd * (q + 1) : rr * (q + 1) + (xcd - rr) * q) + loc;
    const int ks  = swz / nTilesMN;
    const int rem = swz - ks * nTilesMN;
    const int m0 = (rem / nTilesN) * 128;
    const int n0 = (rem % nTilesN) * 128;
    const int kOff = ks * kLen;

    const int tid = threadIdx.x;
    const int wv = tid >> 6;
    const int lane = tid & 63;
    const int wr = wv >> 1;          // 0..1 (M)
    const int wc = wv & 1;           // 0..1 (N)

    f32x4 zero4 = {0.0f, 0.0f, 0.0f, 0.0f};
    f32x4 acc[4][4];
#pragma unroll
    for (int i = 0; i < 4; ++i)
#pragma unroll
        for (int j = 0; j < 4; ++j) acc[i][j] = zero4;

    // staging: each wave stages 32 rows of A and 32 rows of B (4 chunks of
    // 8 rows x 64 shorts). lane -> (lrow=lane>>3, blk=lane&7);
    // source col-block = blk ^ lrow (chunk bases are multiples of 8 rows).
    const int lrow = lane >> 3;
    const int scb = (lane & 7) ^ lrow;
    const unsigned short* ag = A  + (size_t)(m0 + wv * 32 + lrow) * K + kOff + scb * 8;
    const unsigned short* bg = Bt + (size_t)(n0 + wv * 32 + lrow) * K + kOff + scb * 8;
    unsigned short* aLds = As + wv * 32 * 64;
    unsigned short* bLds = Bs + wv * 32 * 64;

    // fragment-read setup
    const int fr = lane & 15;
    const int fg = lane >> 4;        // 0..3
    const int sw = fr & 7;
    const int aRow = (wr * 64 + fr) * 64;   // + mm*16*64
    const int bRow = (wc * 64 + fr) * 64;   // + nn*16*64

    const int nk = kLen >> 6;
    for (int kt = 0; kt < nk; ++kt) {
        const int k0 = kt << 6;
        __syncthreads();
#pragma unroll
        for (int c = 0; c < 4; ++c)
            gload_lds16(ag + k0 + (size_t)c * 8 * K, aLds + c * 512);
#pragma unroll
        for (int c = 0; c < 4; ++c)
            gload_lds16(bg + k0 + (size_t)c * 8 * K, bLds + c * 512);
        __syncthreads();

#pragma unroll
        for (int kk = 0; kk < 2; ++kk) {
            bf16x8 afr[4], bfr[4];
            const int cb = ((kk * 4 + fg) ^ sw) << 3;
#pragma unroll
            for (int mm = 0; mm < 4; ++mm)
                afr[mm] = *(const bf16x8*)(As + aRow + mm * 1024 + cb);
#pragma unroll
            for (int nn = 0; nn < 4; ++nn)
                bfr[nn] = *(const bf16x8*)(Bs + bRow + nn * 1024 + cb);
#pragma unroll
            for (int mm = 0; mm < 4; ++mm)
#pragma unroll
                for (int nn = 0; nn < 4; ++nn)
                    acc[mm][nn] = MFMA16(afr[mm], bfr[nn], acc[mm][nn]);
        }
    }

    // ---- epilogue
    const int lc = lane & 15;
    const int lr = (lane >> 4) * 4;

    if (MODE == 4 && n0 >= 1536) {
        // V tile: LDS-bounce transpose -> vtb[b][d][t] with us8 (16B) stores.
        __syncthreads();   // all waves done reading As/Bs
        unsigned short* Vl = As + wv * 4096;   // [64 d][64 t] shorts, swizzled
#pragma unroll
        for (int mm = 0; mm < 4; ++mm) {
            const int s = mm * 4 + (lane >> 4);     // 8B t-slot 0..15
            const int sp = s >> 1, so = s & 1;      // 16B pair + half
#pragma unroll
            for (int nn = 0; nn < 4; ++nn) {
                const int d = nn * 16 + lc;
                const float bv = bias3[(n0 - 1536) + wc * 64 + d];
                us4 pk;
#pragma unroll
                for (int r = 0; r < 4; ++r) pk[r] = f2bf(acc[mm][nn][r] + bv);
                *(us4*)(Vl + d * 64 + ((sp ^ (d & 7)) << 3) + so * 4) = pk;
            }
        }
        asm volatile("s_waitcnt lgkmcnt(0)" ::: "memory");
        const int bb = m0 >> 11;                 // batch = m0/2048
        const int tl0 = (m0 & 2047) + wr * 64;   // t-base of this wave
        const size_t rowbase = (size_t)(bb * D_ + (n0 - 1536) + wc * 64);
        unsigned short* vout = (unsigned short*)out3;
#pragma unroll
        for (int it = 0; it < 8; ++it) {
            const int d = (lane >> 3) + it * 8;
            const int c = lane & 7;              // 16B t-chunk
            const us8 v = *(const us8*)(Vl + d * 64 + ((c ^ (d & 7)) << 3));
            *(us8*)(vout + (rowbase + d) * (size_t)T_ + tl0 + c * 8) = v;
        }
        return;
    }

#pragma unroll
    for (int mm = 0; mm < 4; ++mm) {
        const int gm0 = m0 + wr * 64 + mm * 16 + lr;
#pragma unroll
        for (int nn = 0; nn < 4; ++nn) {
            const int gn = n0 + wc * 64 + nn * 16 + lc;
            if (MODE == 4) {
                const bool isQ = (n0 < 768);
                unsigned short* o = isQ ? (unsigned short*)outp : (unsigned short*)out2;
                const int col = isQ ? gn : gn - 768;
                const float bv = isQ ? bias[col] : bias2[col];
#pragma unroll
                for (int r = 0; r < 4; ++r)
                    o[(size_t)(gm0 + r) * 768 + col] = f2bf(acc[mm][nn][r] + bv);
            } else if (MODE == 5) {
                unsigned short* o = (unsigned short*)outp + (size_t)ks * partStride;
#pragma unroll
                for (int r = 0; r < 4; ++r)
                    o[(size_t)(gm0 + r) * N + gn] = f2bf(acc[mm][nn][r]);
            } else {
                const float bv = bias[gn];
#pragma unroll
                for (int r = 0; r < 4; ++r) {
                    const int gm = gm0 + r;
                    float v = acc[mm][nn][r] + bv;
                    if (MODE == 0) {
                        ((unsigned short*)outp)[(size_t)gm * N + gn] = f2bf(v);
                    } else if (MODE == 2) {
                        ((unsigned short*)outp)[(size_t)gm * N + gn] = f2bf(gelu_fast(v));
                    }
                }
            }
        }
    }
}

// ---------------- banded flash attention ----------------
// block = 256 threads (4 waves), handles (b, h, 64-query tile).
// T1 XCD swizzle: 1536 blocks % 8 == 0 -> consecutive logical tiles (adjacent
// qt, sharing 128/192 K/V rows) land on the SAME XCD L2.
__global__ __launch_bounds__(256) void attn_kernel(
    const unsigned short* __restrict__ Q,    // [B*T][768]
    const unsigned short* __restrict__ Kg,   // [B*T][768]
    const unsigned short* __restrict__ Vt,   // [B][768][T]
    unsigned short* __restrict__ ctx)        // [B*T][768]
{
    __shared__ __align__(16) unsigned short Qs[64][72];
    __shared__ __align__(16) unsigned short KP[192 * 72];   // Ks, later Ps[64][200]
    __shared__ __align__(16) unsigned short Vts[64][200];

    const int tid = threadIdx.x;
    const int lane = tid & 63;
    const int w = tid >> 6;
    // bijective XCD swizzle (nwg = 1536 = 8 * 192)
    const int bid = (blockIdx.x & 7) * 192 + (blockIdx.x >> 3);
    const int qt = bid & 31;
    const int h = (bid >> 5) % H_;
    const int b = bid / (32 * H_);
    const int qs = qt * 64;
    const int t0 = qs >= 64 ? qs - 64 : 0;
    const int t1 = (qs + 128 < T_) ? qs + 128 : T_;
    const int KW = t1 - t0;

    for (int s = tid; s < 512; s += 256) {
        const int r = s >> 3, c8 = (s & 7) << 3;
        *(uint4*)&Qs[r][c8] =
            *(const uint4*)&Q[((size_t)(b * T_ + qs + r)) * D_ + h * DH_ + c8];
    }
    unsigned short* Ks = KP;
    for (int s = tid; s < 1536; s += 256) {
        const int r = s >> 3, c8 = (s & 7) << 3;
        uint4 val = {0, 0, 0, 0};
        if (r < KW)
            val = *(const uint4*)&Kg[((size_t)(b * T_ + t0 + r)) * D_ + h * DH_ + c8];
        *(uint4*)&Ks[r * 72 + c8] = val;
    }
    for (int s = tid; s < 1536; s += 256) {
        const int r = s / 24, c8 = (s % 24) << 3;
        uint4 val = {0, 0, 0, 0};
        if (c8 < KW)
            val = *(const uint4*)&Vt[((size_t)((b * H_ + h) * DH_ + r)) * T_ + t0 + c8];
        *(uint4*)&Vts[r][c8] = val;
    }
    __syncthreads();

    f32x4 zero4 = {0.0f, 0.0f, 0.0f, 0.0f};
    f32x4 sa[12];
#pragma unroll
    for (int i = 0; i < 12; ++i) sa[i] = zero4;
#pragma unroll
    for (int ks = 0; ks < 2; ++ks) {
        const bf16x8 aq = *(const bf16x8*)&Qs[w * 16 + (lane & 15)][ks * 32 + (lane >> 4) * 8];
#pragma unroll
        for (int cf = 0; cf < 12; ++cf) {
            const bf16x8 bk = *(const bf16x8*)&Ks[(cf * 16 + (lane & 15)) * 72 + ks * 32 + (lane >> 4) * 8];
            sa[cf] = MFMA16(aq, bk, sa[cf]);
        }
    }
    __syncthreads();

    const int lq = w * 16 + (lane >> 4) * 4;
    float mx[4] = {-1e30f, -1e30f, -1e30f, -1e30f};
#pragma unroll
    for (int cf = 0; cf < 12; ++cf) {
        const int key = t0 + cf * 16 + (lane & 15);
#pragma unroll
        for (int r = 0; r < 4; ++r) {
            const int dd = (qs + lq + r) - key;
            const bool ok = (key < t1) && (dd <= 64) && (dd >= -64);
            const float sv = ok ? sa[cf][r] * 0.125f : -1e30f;
            sa[cf][r] = sv;
            mx[r] = fmaxf(mx[r], sv);
        }
    }
#pragma unroll
    for (int r = 0; r < 4; ++r)
#pragma unroll
        for (int o = 1; o < 16; o <<= 1)
            mx[r] = fmaxf(mx[r], __shfl_xor(mx[r], o));

    unsigned short* Ps = KP;
    float sm[4] = {0.0f, 0.0f, 0.0f, 0.0f};
#pragma unroll
    for (int cf = 0; cf < 12; ++cf) {
#pragma unroll
        for (int r = 0; r < 4; ++r) {
            const float p = __expf(sa[cf][r] - mx[r]);
            sm[r] += p;
            Ps[(lq + r) * 200 + cf * 16 + (lane & 15)] = f2bf(p);
        }
    }
#pragma unroll
    for (int r = 0; r < 4; ++r)
#pragma unroll
        for (int o = 1; o < 16; o <<= 1)
            sm[r] += __shfl_xor(sm[r], o);

    f32x4 oa[4];
#pragma unroll
    for (int i = 0; i < 4; ++i) oa[i] = zero4;
#pragma unroll
    for (int ks = 0; ks < 6; ++ks) {
        const bf16x8 ap = *(const bf16x8*)&Ps[(w * 16 + (lane & 15)) * 200 + ks * 32 + (lane >> 4) * 8];
#pragma unroll
        for (int nf = 0; nf < 4; ++nf) {
            const bf16x8 bv = *(const bf16x8*)&Vts[nf * 16 + (lane & 15)][ks * 32 + (lane >> 4) * 8];
            oa[nf] = MFMA16(ap, bv, oa[nf]);
        }
    }
#pragma unroll
    for (int nf = 0; nf < 4; ++nf) {
#pragma unroll
        for (int r = 0; r < 4; ++r) {
            const float o = oa[nf][r] / sm[r];
            ctx[((size_t)(b * T_ + qs + lq + r)) * D_ + h * DH_ + nf * 16 + (lane & 15)] = f2bf(o);
        }
    }
}

// ---------------- orchestration ----------------
extern "C" void kernel_launch(void* const* d_in, const int* in_sizes, int n_in,
                              void* d_out, int out_size, void* d_ws, size_t ws_size,
                              hipStream_t stream)
{
    const float* x   = (const float*)d_in[0];
    const float* Wq  = (const float*)d_in[1];
    const float* bq  = (const float*)d_in[2];
    const float* Wk  = (const float*)d_in[3];
    const float* bk  = (const float*)d_in[4];
    const float* Wv  = (const float*)d_in[5];
    const float* bv  = (const float*)d_in[6];
    const float* Wo  = (const float*)d_in[7];
    const float* bo  = (const float*)d_in[8];
    const float* W1  = (const float*)d_in[9];
    const float* b1  = (const float*)d_in[10];
    const float* W2  = (const float*)d_in[11];
    const float* b2  = (const float*)d_in[12];
    const float* g1  = (const float*)d_in[13];
    const float* be1 = (const float*)d_in[14];
    const float* g2  = (const float*)d_in[15];
    const float* be2 = (const float*)d_in[16];
    float* out = (float*)d_out;

    unsigned short* wqkv_t = (unsigned short*)d_ws;        // 3 x [768][768] (+wo)
    unsigned short* wo_t = wqkv_t + 3 * 589824;
    unsigned short* w1_t = wo_t + 589824;                  // [3072][768]
    unsigned short* w2_t = w1_t + 2359296;                 // [768][3072]
    unsigned short* hbuf = w2_t + 2359296;                 // h1, ctx, FF2-partials
    unsigned short* qbuf = hbuf + 6291456;                 // q, h2, FF2-partial hi
    unsigned short* x2b  = qbuf + 6291456;                 // x2 bf16
    unsigned short* kbuf = x2b + 2 * 6291456;              // k, Wo-partials
    unsigned short* vtb  = kbuf + 6291456;                 // [4][768][2048], Wo-partial hi
    unsigned short* ffb  = kbuf;                           // [8192][3072]

    // fused prep: all 6 weight transposes + LN1 in one launch
    prep_kernel<<<8960, 256, 0, stream>>>(
        Wq, Wk, Wv, Wo, W1, W2, wqkv_t, w1_t, w2_t, x, g1, be1, hbuf);

    // fused QKV: N = 2304, routes Q->qbuf, K->kbuf, V->vtb(transposed)
    gemm4w<4><<<64 * 18, 256, 0, stream>>>(
        hbuf, wqkv_t, bq, bk, bv, qbuf, kbuf, vtb, 2304, 768, 768, 18, 64 * 18, 0);

    attn_kernel<<<1536, 256, 0, stream>>>(qbuf, kbuf, vtb, hbuf);   // ctx -> hbuf

    // Wo: split-K S=2 (K'=384), bf16 partials into dead kbuf/vtb region
    gemm4w<5><<<64 * 6 * 2, 256, 0, stream>>>(
        hbuf, wo_t, nullptr, nullptr, nullptr, kbuf, nullptr, nullptr,
        768, 768, 384, 6, 64 * 6, 6291456);

    // fused reduce + residual + LN2: x2 (bf16) and h2 (bf16 -> qbuf)
    reduce_ln_kernel<<<2048, 256, 0, stream>>>(
        kbuf, kbuf + 6291456, x, bo, g2, be2, x2b, qbuf);

    // FF1: gelu_fast -> ffb (overwrites dead Wo partials)
    gemm4w<2><<<64 * 24, 256, 0, stream>>>(
        qbuf, w1_t, b1, nullptr, nullptr, ffb, nullptr, nullptr,
        3072, 768, 768, 24, 64 * 24, 0);

    // FF2: split-K S=2 (K'=1536), bf16 partials into dead hbuf/qbuf region
    gemm4w<5><<<64 * 6 * 2, 256, 0, stream>>>(
        ffb, w2_t, nullptr, nullptr, nullptr, hbuf, nullptr, nullptr,
        768, 3072, 1536, 6, 64 * 6, 6291456);

    reduce_out_kernel<<<2048, 256, 0, stream>>>(
        hbuf, hbuf + 6291456, x2b, b2, out);
}